// Round 1
// baseline (319.407 us; speedup 1.0000x reference)
//
#include <hip/hip_runtime.h>

typedef __bf16 bf16x8 __attribute__((ext_vector_type(8)));
typedef __bf16 bf16x4 __attribute__((ext_vector_type(4)));
typedef float f32x4 __attribute__((ext_vector_type(4)));

#define MFMA16(a, b, c) __builtin_amdgcn_mfma_f32_16x16x32_bf16((a), (b), (c), 0, 0, 0)

__device__ __forceinline__ void gload_lds16(const void* g, void* l) {
  __builtin_amdgcn_global_load_lds(
      (const __attribute__((address_space(1))) unsigned int*)g,
      (__attribute__((address_space(3))) unsigned int*)l, 16, 0, 0);
}

// ---------------------------------------------------------------------------
// Sliding-window attention: one block per (b, h, chunk). 8 waves x 32 q-rows.
// q = k = v = src (no projection). Window: |k_pos - q_pos| <= 256, in-bounds.
// ---------------------------------------------------------------------------
__global__ __launch_bounds__(512) void attn_kernel(const float* __restrict__ src,
                                                   float* __restrict__ attn_out) {
  const int bid = blockIdx.x;
  const int c = bid & 15;
  const int h = (bid >> 4) & 15;
  const int b = bid >> 8;
  const int tid = threadIdx.x;
  const int w = tid >> 6;
  const int lane = tid & 63;
  const int lg = lane >> 4;
  const int l16 = lane & 15;

  __shared__ __bf16 Ks[64][72];      // K tile row-major [key][d], pad 72
  __shared__ __bf16 Vt[64 * 72];     // V^T tile [d][key], XOR-swizzled col blocks
  __shared__ __bf16 Ps[8][32][72];   // per-wave P scratch [q_local][key], pad 72

  const int q0 = c * 256 + w * 32;   // global q position of this wave's row 0

  // Q fragments (A-operand layout): row = l16, k = 8*lg + j (+32*ks)
  bf16x8 qf[2][2];
#pragma unroll
  for (int rf = 0; rf < 2; ++rf)
#pragma unroll
    for (int ks = 0; ks < 2; ++ks) {
      const int row = q0 + rf * 16 + l16;
      const int d0 = ks * 32 + lg * 8;
      const float* p = src + ((size_t)(b * 4096 + row) * 1024) + h * 64 + d0;
      bf16x8 v;
#pragma unroll
      for (int j = 0; j < 8; ++j) v[j] = (__bf16)p[j];
      qf[rf][ks] = v;
    }

  const f32x4 z4 = {0.f, 0.f, 0.f, 0.f};
  float m_run[2][4], l_run[2][4];
  f32x4 o[2][4];
#pragma unroll
  for (int rf = 0; rf < 2; ++rf) {
#pragma unroll
    for (int r = 0; r < 4; ++r) { m_run[rf][r] = -6.0e8f; l_run[rf][r] = 0.f; }
#pragma unroll
    for (int df = 0; df < 4; ++df) o[rf][df] = z4;
  }

  const int stage_key = tid >> 3;
  const int stage_d0 = (tid & 7) * 8;

  for (int kt = 0; kt < 12; ++kt) {
    const int kbase = c * 256 - 256 + kt * 64;
    __syncthreads();  // protect K/V LDS from previous iteration's readers
    {
      const int kpos = kbase + stage_key;
      bf16x8 kv;
      if (kpos >= 0 && kpos < 4096) {
        const float* p = src + ((size_t)(b * 4096 + kpos) * 1024) + h * 64 + stage_d0;
#pragma unroll
        for (int j = 0; j < 8; ++j) kv[j] = (__bf16)p[j];
      } else {
#pragma unroll
        for (int j = 0; j < 8; ++j) kv[j] = (__bf16)0.f;
      }
      *(bf16x8*)&Ks[stage_key][stage_d0] = kv;
      // V^T with col-block swizzle: idx(d,key) = d*72 + ((key>>3)^(d>>3))*8 + (key&7)
      const int cb = ((stage_key >> 3) ^ (tid & 7)) * 8 + (stage_key & 7);
#pragma unroll
      for (int j = 0; j < 8; ++j) Vt[(stage_d0 + j) * 72 + cb] = kv[j];
    }
    __syncthreads();

    const bool skip = (kbase + 63 < 0) | (kbase >= 4096) |
                      (kbase + 63 < q0 - 256) | (kbase > q0 + 31 + 256);
    if (skip) continue;

    // ---- S = Q K^T (2 rf x 4 cf fragments of 16x16) ----
    f32x4 s[2][4];
#pragma unroll
    for (int rf = 0; rf < 2; ++rf)
#pragma unroll
      for (int cf = 0; cf < 4; ++cf) s[rf][cf] = z4;

#pragma unroll
    for (int ks = 0; ks < 2; ++ks) {
      bf16x8 kf[4];
#pragma unroll
      for (int cf = 0; cf < 4; ++cf)
        kf[cf] = *(const bf16x8*)&Ks[cf * 16 + l16][ks * 32 + lg * 8];
#pragma unroll
      for (int rf = 0; rf < 2; ++rf)
#pragma unroll
        for (int cf = 0; cf < 4; ++cf)
          s[rf][cf] = MFMA16(qf[rf][ks], kf[cf], s[rf][cf]);
    }

    // ---- mask + online softmax (C-layout: row = 4*lg + reg, col = l16) ----
#pragma unroll
    for (int rf = 0; rf < 2; ++rf) {
      float tm[4];
#pragma unroll
      for (int reg = 0; reg < 4; ++reg) {
        const int qp = q0 + rf * 16 + lg * 4 + reg;
#pragma unroll
        for (int cf = 0; cf < 4; ++cf) {
          const int kp = kbase + cf * 16 + l16;
          const int rel = kp - qp;
          if (rel > 256 || rel < -256 || kp < 0 || kp >= 4096) s[rf][cf][reg] = -1e9f;
        }
        tm[reg] = fmaxf(fmaxf(s[rf][0][reg], s[rf][1][reg]),
                        fmaxf(s[rf][2][reg], s[rf][3][reg]));
      }
#pragma unroll
      for (int off = 1; off < 16; off <<= 1)
#pragma unroll
        for (int reg = 0; reg < 4; ++reg)
          tm[reg] = fmaxf(tm[reg], __shfl_xor(tm[reg], off, 64));

      float pr[4];
#pragma unroll
      for (int reg = 0; reg < 4; ++reg) {
        const float mn = fmaxf(m_run[rf][reg], tm[reg]);
        const float scl = __expf(m_run[rf][reg] - mn);
        m_run[rf][reg] = mn;
        l_run[rf][reg] *= scl;
#pragma unroll
        for (int df = 0; df < 4; ++df) o[rf][df][reg] *= scl;
        float rs = 0.f;
#pragma unroll
        for (int cf = 0; cf < 4; ++cf) {
          const float p = __expf(s[rf][cf][reg] - mn);
          s[rf][cf][reg] = p;
          rs += p;
        }
        pr[reg] = rs;
      }
#pragma unroll
      for (int off = 1; off < 16; off <<= 1)
#pragma unroll
        for (int reg = 0; reg < 4; ++reg) pr[reg] += __shfl_xor(pr[reg], off, 64);
#pragma unroll
      for (int reg = 0; reg < 4; ++reg) l_run[rf][reg] += pr[reg];

      // write P (bf16) to per-wave LDS scratch
#pragma unroll
      for (int cf = 0; cf < 4; ++cf)
#pragma unroll
        for (int reg = 0; reg < 4; ++reg)
          Ps[w][rf * 16 + lg * 4 + reg][cf * 16 + l16] = (__bf16)s[rf][cf][reg];
    }
    // cross-lane LDS write -> read hazard within the wave: drain DS queue.
    asm volatile("s_waitcnt lgkmcnt(0)" ::: "memory");

    // ---- O += P V ----
#pragma unroll
    for (int ks = 0; ks < 2; ++ks) {
      bf16x8 pa[2], vb[4];
#pragma unroll
      for (int rf = 0; rf < 2; ++rf)
        pa[rf] = *(const bf16x8*)&Ps[w][rf * 16 + l16][ks * 32 + lg * 8];
#pragma unroll
      for (int df = 0; df < 4; ++df) {
        const int d = df * 16 + l16;
        const int cb2 = ((ks * 4 + lg) ^ (d >> 3)) & 7;
        vb[df] = *(const bf16x8*)&Vt[d * 72 + cb2 * 8];
      }
#pragma unroll
      for (int rf = 0; rf < 2; ++rf)
#pragma unroll
        for (int df = 0; df < 4; ++df)
          o[rf][df] = MFMA16(pa[rf], vb[df], o[rf][df]);
    }
  }

  // epilogue: O /= l, store to attn_out[b][pos][h*64+d]
#pragma unroll
  for (int rf = 0; rf < 2; ++rf)
#pragma unroll
    for (int reg = 0; reg < 4; ++reg) {
      const int qp = q0 + rf * 16 + lg * 4 + reg;
      const float inv = 1.0f / l_run[rf][reg];
      float* dst = attn_out + ((size_t)(b * 4096 + qp)) * 1024 + h * 64 + l16;
#pragma unroll
      for (int df = 0; df < 4; ++df) dst[df * 16] = o[rf][df][reg] * inv;
    }
}

// ---------------------------------------------------------------------------
// NT GEMM (A[M][K] bf16, Bt[N][K] bf16): m97 structure, 128x128 tile, BK=64,
// 4 waves (2x2), global_load_lds width 16, 16x16x32 bf16 MFMA.
// MODE 0: out bf16, +bias, relu.  MODE 1: out f32, +bias.
// ---------------------------------------------------------------------------
template <int MODE>
__global__ __launch_bounds__(256) void gemm_nt(const __bf16* __restrict__ A,
                                               const __bf16* __restrict__ Bt,
                                               const float* __restrict__ bias,
                                               void* __restrict__ out,
                                               int M, int N, int K) {
  __shared__ __bf16 As[128 * 64];
  __shared__ __bf16 Bs[128 * 64];
  const int tid = threadIdx.x;
  const int w = tid >> 6;
  const int lane = tid & 63;
  const int lg = lane >> 4;
  const int l16 = lane & 15;
  const int wr = w >> 1, wc = w & 1;
  const long bm = (long)blockIdx.y * 128;
  const long bn = (long)blockIdx.x * 128;

  const f32x4 z4 = {0.f, 0.f, 0.f, 0.f};
  f32x4 acc[4][4];
#pragma unroll
  for (int i = 0; i < 4; ++i)
#pragma unroll
    for (int j = 0; j < 4; ++j) acc[i][j] = z4;

  const int srow = tid >> 3;
  const int sc8 = (tid & 7) * 8;
  const int nk = K >> 6;

  for (int kt = 0; kt < nk; ++kt) {
    const int k0 = kt << 6;
    __syncthreads();
#pragma unroll
    for (int i = 0; i < 4; ++i) {
      const int row = i * 32 + srow;
      gload_lds16(A + (bm + row) * (long)K + k0 + sc8, As + (i * 2048 + w * 512));
      gload_lds16(Bt + (bn + row) * (long)K + k0 + sc8, Bs + (i * 2048 + w * 512));
    }
    __syncthreads();
#pragma unroll
    for (int ks = 0; ks < 2; ++ks) {
      bf16x8 af[4], bfr[4];
#pragma unroll
      for (int rf = 0; rf < 4; ++rf)
        af[rf] = *(const bf16x8*)&As[(wr * 64 + rf * 16 + l16) * 64 + ks * 32 + lg * 8];
#pragma unroll
      for (int cf = 0; cf < 4; ++cf)
        bfr[cf] = *(const bf16x8*)&Bs[(wc * 64 + cf * 16 + l16) * 64 + ks * 32 + lg * 8];
#pragma unroll
      for (int rf = 0; rf < 4; ++rf)
#pragma unroll
        for (int cf = 0; cf < 4; ++cf)
          acc[rf][cf] = MFMA16(af[rf], bfr[cf], acc[rf][cf]);
    }
  }

  float bv[4];
#pragma unroll
  for (int cf = 0; cf < 4; ++cf) bv[cf] = bias[bn + wc * 64 + cf * 16 + l16];
#pragma unroll
  for (int rf = 0; rf < 4; ++rf)
#pragma unroll
    for (int reg = 0; reg < 4; ++reg) {
      const long row = bm + wr * 64 + rf * 16 + lg * 4 + reg;
#pragma unroll
      for (int cf = 0; cf < 4; ++cf) {
        const long col = bn + wc * 64 + cf * 16 + l16;
        float v = acc[rf][cf][reg] + bv[cf];
        if (MODE == 0) {
          v = fmaxf(v, 0.f);
          ((__bf16*)out)[row * N + col] = (__bf16)v;
        } else {
          ((float*)out)[row * N + col] = v;
        }
      }
    }
}

// ---------------------------------------------------------------------------
// W [R][C] f32 -> Wt [C][R] bf16 (tiled transpose via LDS)
// ---------------------------------------------------------------------------
__global__ __launch_bounds__(256) void transpose_cvt(const float* __restrict__ in,
                                                     __bf16* __restrict__ out,
                                                     int R, int C) {
  __shared__ float tile[64][65];
  const long r0 = (long)blockIdx.y * 64;
  const long c0 = (long)blockIdx.x * 64;
  const int t = threadIdx.x;
  const int tr = t >> 6;
  const int tc = t & 63;
#pragma unroll
  for (int i = 0; i < 16; ++i) {
    const int r = tr * 16 + i;
    tile[r][tc] = in[(r0 + r) * C + c0 + tc];
  }
  __syncthreads();
#pragma unroll
  for (int i = 0; i < 16; ++i) {
    const int cc = tr * 16 + i;
    out[(c0 + cc) * (long)R + r0 + tc] = (__bf16)tile[tc][cc];
  }
}

// ---------------------------------------------------------------------------
// LayerNorm kernels: one row (1024) per 256-thread block.
// ---------------------------------------------------------------------------
__global__ __launch_bounds__(256) void ln1_kernel(const float* __restrict__ src,
                                                  const float* __restrict__ attn,
                                                  const float* __restrict__ g,
                                                  const float* __restrict__ bta,
                                                  __bf16* __restrict__ xb) {
  const long r = blockIdx.x;
  const int t = threadIdx.x;
  const float4 a = *(const float4*)&src[r * 1024 + t * 4];
  const float4 cc = *(const float4*)&attn[r * 1024 + t * 4];
  float v[4] = {a.x + cc.x, a.y + cc.y, a.z + cc.z, a.w + cc.w};
  float s = v[0] + v[1] + v[2] + v[3];
  float s2 = v[0] * v[0] + v[1] * v[1] + v[2] * v[2] + v[3] * v[3];
#pragma unroll
  for (int off = 32; off >= 1; off >>= 1) {
    s += __shfl_xor(s, off, 64);
    s2 += __shfl_xor(s2, off, 64);
  }
  __shared__ float red[8];
  if ((t & 63) == 0) { red[t >> 6] = s; red[(t >> 6) + 4] = s2; }
  __syncthreads();
  s = red[0] + red[1] + red[2] + red[3];
  s2 = red[4] + red[5] + red[6] + red[7];
  const float mu = s * (1.f / 1024.f);
  const float var = s2 * (1.f / 1024.f) - mu * mu;
  const float rstd = rsqrtf(var + 1e-5f);
  const float4 gv = *(const float4*)&g[t * 4];
  const float4 bv = *(const float4*)&bta[t * 4];
  bf16x4 y;
  y[0] = (__bf16)((v[0] - mu) * rstd * gv.x + bv.x);
  y[1] = (__bf16)((v[1] - mu) * rstd * gv.y + bv.y);
  y[2] = (__bf16)((v[2] - mu) * rstd * gv.z + bv.z);
  y[3] = (__bf16)((v[3] - mu) * rstd * gv.w + bv.w);
  *(bf16x4*)&xb[r * 1024 + t * 4] = y;
}

__global__ __launch_bounds__(256) void ln2_kernel(const __bf16* __restrict__ xb,
                                                  const float* __restrict__ ff,
                                                  const float* __restrict__ g,
                                                  const float* __restrict__ bta,
                                                  float* __restrict__ out) {
  const long r = blockIdx.x;
  const int t = threadIdx.x;
  const bf16x4 xv = *(const bf16x4*)&xb[r * 1024 + t * 4];
  const float4 fv = *(const float4*)&ff[r * 1024 + t * 4];
  float v[4] = {(float)xv[0] + fv.x, (float)xv[1] + fv.y,
                (float)xv[2] + fv.z, (float)xv[3] + fv.w};
  float s = v[0] + v[1] + v[2] + v[3];
  float s2 = v[0] * v[0] + v[1] * v[1] + v[2] * v[2] + v[3] * v[3];
#pragma unroll
  for (int off = 32; off >= 1; off >>= 1) {
    s += __shfl_xor(s, off, 64);
    s2 += __shfl_xor(s2, off, 64);
  }
  __shared__ float red[8];
  if ((t & 63) == 0) { red[t >> 6] = s; red[(t >> 6) + 4] = s2; }
  __syncthreads();
  s = red[0] + red[1] + red[2] + red[3];
  s2 = red[4] + red[5] + red[6] + red[7];
  const float mu = s * (1.f / 1024.f);
  const float var = s2 * (1.f / 1024.f) - mu * mu;
  const float rstd = rsqrtf(var + 1e-5f);
  const float4 gv = *(const float4*)&g[t * 4];
  const float4 bv = *(const float4*)&bta[t * 4];
  float4 y;
  y.x = (v[0] - mu) * rstd * gv.x + bv.x;
  y.y = (v[1] - mu) * rstd * gv.y + bv.y;
  y.z = (v[2] - mu) * rstd * gv.z + bv.z;
  y.w = (v[3] - mu) * rstd * gv.w + bv.w;
  *(float4*)&out[r * 1024 + t * 4] = y;
}

// ---------------------------------------------------------------------------
extern "C" void kernel_launch(void* const* d_in, const int* in_sizes, int n_in,
                              void* d_out, int out_size, void* d_ws, size_t ws_size,
                              hipStream_t stream) {
  const float* src = (const float*)d_in[0];
  const float* ln1_g = (const float*)d_in[1];
  const float* ln1_b = (const float*)d_in[2];
  const float* ln2_g = (const float*)d_in[3];
  const float* ln2_b = (const float*)d_in[4];
  const float* W1 = (const float*)d_in[5];
  const float* b1 = (const float*)d_in[6];
  const float* W2 = (const float*)d_in[7];
  const float* b2 = (const float*)d_in[8];
  float* out = (float*)d_out;
  char* ws = (char*)d_ws;

  float* attn_ff = (float*)ws;                                  // 32 MB (attn, then ff)
  __bf16* xb = (__bf16*)(ws + 33554432);                        // 16 MB
  __bf16* w1t = (__bf16*)(ws + 33554432 + 16777216);            // 8 MB
  __bf16* w2t = (__bf16*)(ws + 33554432 + 16777216 + 8388608);  // 8 MB
  __bf16* hbuf = (__bf16*)(ws + 67108864);                      // Mc*4096*2 B

  int Mc = 8192;
  while (Mc > 512 && (67108864ull + (size_t)Mc * 8192ull) > ws_size) Mc >>= 1;

  transpose_cvt<<<dim3(4096 / 64, 1024 / 64), 256, 0, stream>>>(W1, w1t, 1024, 4096);
  transpose_cvt<<<dim3(1024 / 64, 4096 / 64), 256, 0, stream>>>(W2, w2t, 4096, 1024);
  attn_kernel<<<512, 512, 0, stream>>>(src, attn_ff);
  ln1_kernel<<<8192, 256, 0, stream>>>(src, attn_ff, ln1_g, ln1_b, xb);
  for (int m0 = 0; m0 < 8192; m0 += Mc) {
    gemm_nt<0><<<dim3(4096 / 128, Mc / 128), 256, 0, stream>>>(
        xb + (size_t)m0 * 1024, w1t, b1, hbuf, Mc, 4096, 1024);
    gemm_nt<1><<<dim3(1024 / 128, Mc / 128), 256, 0, stream>>>(
        hbuf, w2t, b2, attn_ff + (size_t)m0 * 1024, Mc, 1024, 4096);
  }
  ln2_kernel<<<8192, 256, 0, stream>>>(xb, attn_ff, ln2_g, ln2_b, out);
}

// Round 2
// 287.047 us; speedup vs baseline: 1.1127x; 1.1127x over previous
//
#include <hip/hip_runtime.h>

typedef __bf16 bf16x8 __attribute__((ext_vector_type(8)));
typedef __bf16 bf16x4 __attribute__((ext_vector_type(4)));
typedef float f32x4 __attribute__((ext_vector_type(4)));

#define MFMA16(a, b, c) __builtin_amdgcn_mfma_f32_16x16x32_bf16((a), (b), (c), 0, 0, 0)

__device__ __forceinline__ void gload_lds16(const void* g, void* l) {
  __builtin_amdgcn_global_load_lds(
      (const __attribute__((address_space(1))) unsigned int*)g,
      (__attribute__((address_space(3))) unsigned int*)l, 16, 0, 0);
}

// ---------------------------------------------------------------------------
// Sliding-window attention: one block per (b, h, chunk). 8 waves x 32 q-rows.
// ---------------------------------------------------------------------------
__global__ __launch_bounds__(512) void attn_kernel(const float* __restrict__ src,
                                                   float* __restrict__ attn_out) {
  const int bid = blockIdx.x;
  const int c = bid & 15;
  const int h = (bid >> 4) & 15;
  const int b = bid >> 8;
  const int tid = threadIdx.x;
  const int w = tid >> 6;
  const int lane = tid & 63;
  const int lg = lane >> 4;
  const int l16 = lane & 15;

  __shared__ __bf16 Ks[64][72];
  __shared__ __bf16 Vt[64 * 72];
  __shared__ __bf16 Ps[8][32][72];

  const int q0 = c * 256 + w * 32;

  bf16x8 qf[2][2];
#pragma unroll
  for (int rf = 0; rf < 2; ++rf)
#pragma unroll
    for (int ks = 0; ks < 2; ++ks) {
      const int row = q0 + rf * 16 + l16;
      const int d0 = ks * 32 + lg * 8;
      const float* p = src + ((size_t)(b * 4096 + row) * 1024) + h * 64 + d0;
      bf16x8 v;
#pragma unroll
      for (int j = 0; j < 8; ++j) v[j] = (__bf16)p[j];
      qf[rf][ks] = v;
    }

  const f32x4 z4 = {0.f, 0.f, 0.f, 0.f};
  float m_run[2][4], l_run[2][4];
  f32x4 o[2][4];
#pragma unroll
  for (int rf = 0; rf < 2; ++rf) {
#pragma unroll
    for (int r = 0; r < 4; ++r) { m_run[rf][r] = -6.0e8f; l_run[rf][r] = 0.f; }
#pragma unroll
    for (int df = 0; df < 4; ++df) o[rf][df] = z4;
  }

  const int stage_key = tid >> 3;
  const int stage_d0 = (tid & 7) * 8;

  for (int kt = 0; kt < 12; ++kt) {
    const int kbase = c * 256 - 256 + kt * 64;
    __syncthreads();
    {
      const int kpos = kbase + stage_key;
      bf16x8 kv;
      if (kpos >= 0 && kpos < 4096) {
        const float* p = src + ((size_t)(b * 4096 + kpos) * 1024) + h * 64 + stage_d0;
#pragma unroll
        for (int j = 0; j < 8; ++j) kv[j] = (__bf16)p[j];
      } else {
#pragma unroll
        for (int j = 0; j < 8; ++j) kv[j] = (__bf16)0.f;
      }
      *(bf16x8*)&Ks[stage_key][stage_d0] = kv;
      const int cb = ((stage_key >> 3) ^ (tid & 7)) * 8 + (stage_key & 7);
#pragma unroll
      for (int j = 0; j < 8; ++j) Vt[(stage_d0 + j) * 72 + cb] = kv[j];
    }
    __syncthreads();

    const bool skip = (kbase + 63 < 0) | (kbase >= 4096) |
                      (kbase + 63 < q0 - 256) | (kbase > q0 + 31 + 256);
    if (skip) continue;

    f32x4 s[2][4];
#pragma unroll
    for (int rf = 0; rf < 2; ++rf)
#pragma unroll
      for (int cf = 0; cf < 4; ++cf) s[rf][cf] = z4;

#pragma unroll
    for (int ks = 0; ks < 2; ++ks) {
      bf16x8 kf[4];
#pragma unroll
      for (int cf = 0; cf < 4; ++cf)
        kf[cf] = *(const bf16x8*)&Ks[cf * 16 + l16][ks * 32 + lg * 8];
#pragma unroll
      for (int rf = 0; rf < 2; ++rf)
#pragma unroll
        for (int cf = 0; cf < 4; ++cf)
          s[rf][cf] = MFMA16(qf[rf][ks], kf[cf], s[rf][cf]);
    }

#pragma unroll
    for (int rf = 0; rf < 2; ++rf) {
      float tm[4];
#pragma unroll
      for (int reg = 0; reg < 4; ++reg) {
        const int qp = q0 + rf * 16 + lg * 4 + reg;
#pragma unroll
        for (int cf = 0; cf < 4; ++cf) {
          const int kp = kbase + cf * 16 + l16;
          const int rel = kp - qp;
          if (rel > 256 || rel < -256 || kp < 0 || kp >= 4096) s[rf][cf][reg] = -1e9f;
        }
        tm[reg] = fmaxf(fmaxf(s[rf][0][reg], s[rf][1][reg]),
                        fmaxf(s[rf][2][reg], s[rf][3][reg]));
      }
#pragma unroll
      for (int off = 1; off < 16; off <<= 1)
#pragma unroll
        for (int reg = 0; reg < 4; ++reg)
          tm[reg] = fmaxf(tm[reg], __shfl_xor(tm[reg], off, 64));

      float pr[4];
#pragma unroll
      for (int reg = 0; reg < 4; ++reg) {
        const float mn = fmaxf(m_run[rf][reg], tm[reg]);
        const float scl = __expf(m_run[rf][reg] - mn);
        m_run[rf][reg] = mn;
        l_run[rf][reg] *= scl;
#pragma unroll
        for (int df = 0; df < 4; ++df) o[rf][df][reg] *= scl;
        float rs = 0.f;
#pragma unroll
        for (int cf = 0; cf < 4; ++cf) {
          const float p = __expf(s[rf][cf][reg] - mn);
          s[rf][cf][reg] = p;
          rs += p;
        }
        pr[reg] = rs;
      }
#pragma unroll
      for (int off = 1; off < 16; off <<= 1)
#pragma unroll
        for (int reg = 0; reg < 4; ++reg) pr[reg] += __shfl_xor(pr[reg], off, 64);
#pragma unroll
      for (int reg = 0; reg < 4; ++reg) l_run[rf][reg] += pr[reg];

#pragma unroll
      for (int cf = 0; cf < 4; ++cf)
#pragma unroll
        for (int reg = 0; reg < 4; ++reg)
          Ps[w][rf * 16 + lg * 4 + reg][cf * 16 + l16] = (__bf16)s[rf][cf][reg];
    }
    asm volatile("s_waitcnt lgkmcnt(0)" ::: "memory");

#pragma unroll
    for (int ks = 0; ks < 2; ++ks) {
      bf16x8 pa[2], vb[4];
#pragma unroll
      for (int rf = 0; rf < 2; ++rf)
        pa[rf] = *(const bf16x8*)&Ps[w][rf * 16 + l16][ks * 32 + lg * 8];
#pragma unroll
      for (int df = 0; df < 4; ++df) {
        const int d = df * 16 + l16;
        const int cb2 = ((ks * 4 + lg) ^ (d >> 3)) & 7;
        vb[df] = *(const bf16x8*)&Vt[d * 72 + cb2 * 8];
      }
#pragma unroll
      for (int rf = 0; rf < 2; ++rf)
#pragma unroll
        for (int df = 0; df < 4; ++df)
          o[rf][df] = MFMA16(pa[rf], vb[df], o[rf][df]);
    }
  }

#pragma unroll
  for (int rf = 0; rf < 2; ++rf)
#pragma unroll
    for (int reg = 0; reg < 4; ++reg) {
      const int qp = q0 + rf * 16 + lg * 4 + reg;
      const float inv = 1.0f / l_run[rf][reg];
      float* dst = attn_out + ((size_t)(b * 4096 + qp)) * 1024 + h * 64 + l16;
#pragma unroll
      for (int df = 0; df < 4; ++df) dst[df * 16] = o[rf][df][reg] * inv;
    }
}

// ---------------------------------------------------------------------------
// 8-phase NT GEMM: BM=256, BN=128, BK=64, 8 waves (4Mx2N), per-wave 64x64.
// 3-deep LDS ring (144 KiB) -> stage runs one full K-tile ahead; counted
// vmcnt(6) per K-tile (6 gloads/wave/tile), never drain-to-0.
// T2 swizzle: linear gload_lds dest + pre-swizzled global source col
// ^((row&7)<<4), same XOR on ds_read_b128 -> 2 lanes/bank.
// MODE 0: out bf16, +bias, relu.  MODE 1: out f32, +bias.
// ---------------------------------------------------------------------------
template <int MODE>
__global__ __launch_bounds__(512, 2) void gemm8p(const __bf16* __restrict__ A,
                                                 const __bf16* __restrict__ Bt,
                                                 const float* __restrict__ bias,
                                                 void* __restrict__ out,
                                                 int M, int N, int K) {
  __shared__ char smem[147456];  // A ring 3x32KB @0, B ring 3x16KB @98304
  const int tid = threadIdx.x;
  const int w = tid >> 6;
  const int lane = tid & 63;
  const int lg = lane >> 4;
  const int l16 = lane & 15;
  const int wr = w >> 1;  // 0..3 (M)
  const int wc = w & 1;   // 0..1 (N)

  // XCD-aware bijective swizzle (grid % 8 == 0 for all our launches)
  const int nbn = N >> 7;
  const int x = ((int)blockIdx.x & 7) * ((int)gridDim.x >> 3) + ((int)blockIdx.x >> 3);
  const long bm = (long)(x / nbn) * 256;
  const long bn = (long)(x % nbn) * 128;

  int ao0 = 0, ao1 = 32768, ao2 = 65536;
  int bo0 = 98304, bo1 = 114688, bo2 = 131072;

  const f32x4 z4 = {0.f, 0.f, 0.f, 0.f};
  f32x4 acc[4][4];
#pragma unroll
  for (int i = 0; i < 4; ++i)
#pragma unroll
    for (int j = 0; j < 4; ++j) acc[i][j] = z4;

  // staging: unit = 64 rows x 64 cols bf16 (8KB, 1 gload/thread)
  const int srow = tid >> 3;
  const int scsw = ((tid & 7) << 4) ^ ((srow & 7) << 4);  // pre-swizzled src col
  const char* Ag = (const char*)A + ((size_t)(bm + srow) * K) * 2 + scsw;
  const char* Bg = (const char*)Bt + ((size_t)(bn + srow) * K) * 2 + scsw;
  const size_t ustride = (size_t)K * 128;  // 64 rows * K * 2B
  char* lw = smem + (w << 10);             // wave-uniform LDS staging base

  const unsigned asw = (unsigned)((l16 & 7) << 4);
  const int arow = wr * 64 + l16;
  const int brow = wc * 64 + l16;

  auto stA = [&](int kt, int ao, int u) {
    gload_lds16(Ag + (size_t)u * ustride + (size_t)kt * 128, lw + ao + u * 8192);
  };
  auto stB = [&](int kt, int bo, int v) {
    gload_lds16(Bg + (size_t)v * ustride + (size_t)kt * 128, lw + bo + v * 8192);
  };
  auto rdA = [&](int ao, int rf, int ks) {
    return *(const bf16x8*)(smem + ao + (arow + rf * 16) * 128 +
                            ((unsigned)((ks << 6) | (lg << 4)) ^ asw));
  };
  auto rdB = [&](int bo, int cf, int ks) {
    return *(const bf16x8*)(smem + bo + (brow + cf * 16) * 128 +
                            ((unsigned)((ks << 6) | (lg << 4)) ^ asw));
  };

  const int NT = K >> 6;

  // prologue: stage tiles 0 and 1 (6 gloads/wave each)
#pragma unroll
  for (int u = 0; u < 4; ++u) stA(0, ao0, u);
  stB(0, bo0, 0); stB(0, bo0, 1);
#pragma unroll
  for (int u = 0; u < 4; ++u) stA(1, ao1, u);
  stB(1, bo1, 0); stB(1, bo1, 1);
  asm volatile("s_waitcnt vmcnt(6)" ::: "memory");  // tile 0 landed
  __builtin_amdgcn_s_barrier();

  for (int t = 0; t < NT; ++t) {
    const bool st = (t + 2) < NT;
    const int kt2 = t + 2;
    bf16x8 af[2][2], bl[2][2], bh[2][2];

    // ---- phase 0: read a-lo + b-lo, stage A u0,u1; MFMA quad (rlo, clo) ----
#pragma unroll
    for (int i = 0; i < 2; ++i)
#pragma unroll
      for (int ks = 0; ks < 2; ++ks) af[i][ks] = rdA(ao0, i, ks);
#pragma unroll
    for (int j = 0; j < 2; ++j)
#pragma unroll
      for (int ks = 0; ks < 2; ++ks) bl[j][ks] = rdB(bo0, j, ks);
    if (st) { stA(kt2, ao2, 0); stA(kt2, ao2, 1); }
    __builtin_amdgcn_s_barrier();
    asm volatile("s_waitcnt lgkmcnt(0)" ::: "memory");
    __builtin_amdgcn_s_setprio(1);
#pragma unroll
    for (int i = 0; i < 2; ++i)
#pragma unroll
      for (int j = 0; j < 2; ++j)
#pragma unroll
        for (int ks = 0; ks < 2; ++ks)
          acc[i][j] = MFMA16(af[i][ks], bl[j][ks], acc[i][j]);
    __builtin_amdgcn_s_setprio(0);
    __builtin_amdgcn_s_barrier();

    // ---- phase 1: read b-hi, stage A u2,u3; MFMA quad (rlo, chi) ----
#pragma unroll
    for (int j = 0; j < 2; ++j)
#pragma unroll
      for (int ks = 0; ks < 2; ++ks) bh[j][ks] = rdB(bo0, 2 + j, ks);
    if (st) { stA(kt2, ao2, 2); stA(kt2, ao2, 3); }
    __builtin_amdgcn_s_barrier();
    asm volatile("s_waitcnt lgkmcnt(0)" ::: "memory");
    __builtin_amdgcn_s_setprio(1);
#pragma unroll
    for (int i = 0; i < 2; ++i)
#pragma unroll
      for (int j = 0; j < 2; ++j)
#pragma unroll
        for (int ks = 0; ks < 2; ++ks)
          acc[i][2 + j] = MFMA16(af[i][ks], bh[j][ks], acc[i][2 + j]);
    __builtin_amdgcn_s_setprio(0);
    __builtin_amdgcn_s_barrier();

    // ---- phase 2: read a-hi, stage B u0; MFMA quad (rhi, clo) ----
#pragma unroll
    for (int i = 0; i < 2; ++i)
#pragma unroll
      for (int ks = 0; ks < 2; ++ks) af[i][ks] = rdA(ao0, 2 + i, ks);
    if (st) stB(kt2, bo2, 0);
    __builtin_amdgcn_s_barrier();
    asm volatile("s_waitcnt lgkmcnt(0)" ::: "memory");
    __builtin_amdgcn_s_setprio(1);
#pragma unroll
    for (int i = 0; i < 2; ++i)
#pragma unroll
      for (int j = 0; j < 2; ++j)
#pragma unroll
        for (int ks = 0; ks < 2; ++ks)
          acc[2 + i][j] = MFMA16(af[i][ks], bl[j][ks], acc[2 + i][j]);
    __builtin_amdgcn_s_setprio(0);
    __builtin_amdgcn_s_barrier();

    // ---- phase 3: stage B u1; counted vmcnt(6) -> next tile ready; MFMA ----
    if (st) stB(kt2, bo2, 1);
    asm volatile("s_waitcnt vmcnt(6)" ::: "memory");  // tile t+1's 6 loads done
    __builtin_amdgcn_s_barrier();
    __builtin_amdgcn_s_setprio(1);
#pragma unroll
    for (int i = 0; i < 2; ++i)
#pragma unroll
      for (int j = 0; j < 2; ++j)
#pragma unroll
        for (int ks = 0; ks < 2; ++ks)
          acc[2 + i][2 + j] = MFMA16(af[i][ks], bh[j][ks], acc[2 + i][2 + j]);
    __builtin_amdgcn_s_setprio(0);
    __builtin_amdgcn_s_barrier();

    // rotate ring
    const int ta = ao0; ao0 = ao1; ao1 = ao2; ao2 = ta;
    const int tb = bo0; bo0 = bo1; bo1 = bo2; bo2 = tb;
  }

  float bv[4];
#pragma unroll
  for (int cf = 0; cf < 4; ++cf) bv[cf] = bias[bn + wc * 64 + cf * 16 + l16];
#pragma unroll
  for (int rf = 0; rf < 4; ++rf)
#pragma unroll
    for (int reg = 0; reg < 4; ++reg) {
      const long row = bm + wr * 64 + rf * 16 + lg * 4 + reg;
#pragma unroll
      for (int cf = 0; cf < 4; ++cf) {
        const long col = bn + wc * 64 + cf * 16 + l16;
        float v = acc[rf][cf][reg] + bv[cf];
        if (MODE == 0) {
          ((__bf16*)out)[row * N + col] = (__bf16)fmaxf(v, 0.f);
        } else {
          ((float*)out)[row * N + col] = v;
        }
      }
    }
}

// ---------------------------------------------------------------------------
// W [R][C] f32 -> Wt [C][R] bf16 (tiled transpose via LDS)
// ---------------------------------------------------------------------------
__global__ __launch_bounds__(256) void transpose_cvt(const float* __restrict__ in,
                                                     __bf16* __restrict__ out,
                                                     int R, int C) {
  __shared__ float tile[64][65];
  const long r0 = (long)blockIdx.y * 64;
  const long c0 = (long)blockIdx.x * 64;
  const int t = threadIdx.x;
  const int tr = t >> 6;
  const int tc = t & 63;
#pragma unroll
  for (int i = 0; i < 16; ++i) {
    const int r = tr * 16 + i;
    tile[r][tc] = in[(r0 + r) * C + c0 + tc];
  }
  __syncthreads();
#pragma unroll
  for (int i = 0; i < 16; ++i) {
    const int cc = tr * 16 + i;
    out[(c0 + cc) * (long)R + r0 + tc] = (__bf16)tile[tc][cc];
  }
}

// ---------------------------------------------------------------------------
// LayerNorm kernels: one row (1024) per 256-thread block.
// ---------------------------------------------------------------------------
__global__ __launch_bounds__(256) void ln1_kernel(const float* __restrict__ src,
                                                  const float* __restrict__ attn,
                                                  const float* __restrict__ g,
                                                  const float* __restrict__ bta,
                                                  __bf16* __restrict__ xb) {
  const long r = blockIdx.x;
  const int t = threadIdx.x;
  const float4 a = *(const float4*)&src[r * 1024 + t * 4];
  const float4 cc = *(const float4*)&attn[r * 1024 + t * 4];
  float v[4] = {a.x + cc.x, a.y + cc.y, a.z + cc.z, a.w + cc.w};
  float s = v[0] + v[1] + v[2] + v[3];
  float s2 = v[0] * v[0] + v[1] * v[1] + v[2] * v[2] + v[3] * v[3];
#pragma unroll
  for (int off = 32; off >= 1; off >>= 1) {
    s += __shfl_xor(s, off, 64);
    s2 += __shfl_xor(s2, off, 64);
  }
  __shared__ float red[8];
  if ((t & 63) == 0) { red[t >> 6] = s; red[(t >> 6) + 4] = s2; }
  __syncthreads();
  s = red[0] + red[1] + red[2] + red[3];
  s2 = red[4] + red[5] + red[6] + red[7];
  const float mu = s * (1.f / 1024.f);
  const float var = s2 * (1.f / 1024.f) - mu * mu;
  const float rstd = rsqrtf(var + 1e-5f);
  const float4 gv = *(const float4*)&g[t * 4];
  const float4 bv = *(const float4*)&bta[t * 4];
  bf16x4 y;
  y[0] = (__bf16)((v[0] - mu) * rstd * gv.x + bv.x);
  y[1] = (__bf16)((v[1] - mu) * rstd * gv.y + bv.y);
  y[2] = (__bf16)((v[2] - mu) * rstd * gv.z + bv.z);
  y[3] = (__bf16)((v[3] - mu) * rstd * gv.w + bv.w);
  *(bf16x4*)&xb[r * 1024 + t * 4] = y;
}

__global__ __launch_bounds__(256) void ln2_kernel(const __bf16* __restrict__ xb,
                                                  const float* __restrict__ ff,
                                                  const float* __restrict__ g,
                                                  const float* __restrict__ bta,
                                                  float* __restrict__ out) {
  const long r = blockIdx.x;
  const int t = threadIdx.x;
  const bf16x4 xv = *(const bf16x4*)&xb[r * 1024 + t * 4];
  const float4 fv = *(const float4*)&ff[r * 1024 + t * 4];
  float v[4] = {(float)xv[0] + fv.x, (float)xv[1] + fv.y,
                (float)xv[2] + fv.z, (float)xv[3] + fv.w};
  float s = v[0] + v[1] + v[2] + v[3];
  float s2 = v[0] * v[0] + v[1] * v[1] + v[2] * v[2] + v[3] * v[3];
#pragma unroll
  for (int off = 32; off >= 1; off >>= 1) {
    s += __shfl_xor(s, off, 64);
    s2 += __shfl_xor(s2, off, 64);
  }
  __shared__ float red[8];
  if ((t & 63) == 0) { red[t >> 6] = s; red[(t >> 6) + 4] = s2; }
  __syncthreads();
  s = red[0] + red[1] + red[2] + red[3];
  s2 = red[4] + red[5] + red[6] + red[7];
  const float mu = s * (1.f / 1024.f);
  const float var = s2 * (1.f / 1024.f) - mu * mu;
  const float rstd = rsqrtf(var + 1e-5f);
  const float4 gv = *(const float4*)&g[t * 4];
  const float4 bv = *(const float4*)&bta[t * 4];
  float4 y;
  y.x = (v[0] - mu) * rstd * gv.x + bv.x;
  y.y = (v[1] - mu) * rstd * gv.y + bv.y;
  y.z = (v[2] - mu) * rstd * gv.z + bv.z;
  y.w = (v[3] - mu) * rstd * gv.w + bv.w;
  *(float4*)&out[r * 1024 + t * 4] = y;
}

// ---------------------------------------------------------------------------
extern "C" void kernel_launch(void* const* d_in, const int* in_sizes, int n_in,
                              void* d_out, int out_size, void* d_ws, size_t ws_size,
                              hipStream_t stream) {
  const float* src = (const float*)d_in[0];
  const float* ln1_g = (const float*)d_in[1];
  const float* ln1_b = (const float*)d_in[2];
  const float* ln2_g = (const float*)d_in[3];
  const float* ln2_b = (const float*)d_in[4];
  const float* W1 = (const float*)d_in[5];
  const float* b1 = (const float*)d_in[6];
  const float* W2 = (const float*)d_in[7];
  const float* b2 = (const float*)d_in[8];
  float* out = (float*)d_out;
  char* ws = (char*)d_ws;

  float* attn_ff = (float*)ws;                                  // 32 MB (attn, then ff)
  __bf16* xb = (__bf16*)(ws + 33554432);                        // 16 MB
  __bf16* w1t = (__bf16*)(ws + 33554432 + 16777216);            // 8 MB
  __bf16* w2t = (__bf16*)(ws + 33554432 + 16777216 + 8388608);  // 8 MB
  __bf16* hbuf = (__bf16*)(ws + 67108864);                      // Mc*4096*2 B

  int Mc = 8192;
  while (Mc > 512 && (67108864ull + (size_t)Mc * 8192ull) > ws_size) Mc >>= 1;

  transpose_cvt<<<dim3(4096 / 64, 1024 / 64), 256, 0, stream>>>(W1, w1t, 1024, 4096);
  transpose_cvt<<<dim3(1024 / 64, 4096 / 64), 256, 0, stream>>>(W2, w2t, 4096, 1024);
  attn_kernel<<<512, 512, 0, stream>>>(src, attn_ff);
  ln1_kernel<<<8192, 256, 0, stream>>>(src, attn_ff, ln1_g, ln1_b, xb);
  for (int m0 = 0; m0 < 8192; m0 += Mc) {
    gemm8p<0><<<(Mc / 256) * (4096 / 128), 512, 0, stream>>>(
        xb + (size_t)m0 * 1024, w1t, b1, hbuf, Mc, 4096, 1024);
    gemm8p<1><<<(Mc / 256) * (1024 / 128), 512, 0, stream>>>(
        hbuf, w2t, b2, attn_ff + (size_t)m0 * 1024, Mc, 1024, 4096);
  }
  ln2_kernel<<<8192, 256, 0, stream>>>(xb, attn_ff, ln2_g, ln2_b, out);
}

// Round 4
// 271.717 us; speedup vs baseline: 1.1755x; 1.0564x over previous
//
#include <hip/hip_runtime.h>

typedef __bf16 bf16x8 __attribute__((ext_vector_type(8)));
typedef __bf16 bf16x4 __attribute__((ext_vector_type(4)));
typedef float f32x4 __attribute__((ext_vector_type(4)));

#define MFMA16(a, b, c) __builtin_amdgcn_mfma_f32_16x16x32_bf16((a), (b), (c), 0, 0, 0)

__device__ __forceinline__ void gload_lds16(const void* g, void* l) {
  __builtin_amdgcn_global_load_lds(
      (const __attribute__((address_space(1))) unsigned int*)g,
      (__attribute__((address_space(3))) unsigned int*)l, 16, 0, 0);
}

// ---------------------------------------------------------------------------
// Sliding-window attention, permuted-fragment swapped structure.
// S^T = mfma(K_perm, Q): fragment kf loads key row keymap(kf, l16) =
// (kf>>1)*32 + 8*(l16>>2) + 4*(kf&1) + (l16&3), so the P^T registers are
// DIRECTLY the B-operand of the K=32 PV MFMA (bq[ks2] = pb[2ks2]||pb[2ks2+1]).
// PV computes O^T = mfma(A = V^T[d][k] from LDS, B = P^T): q lives on l16
// everywhere -> softmax state never crosses lanes. Only verified layouts used.
// ---------------------------------------------------------------------------
__global__ __launch_bounds__(512, 2) void attn_kernel(const float* __restrict__ src,
                                                      float* __restrict__ attn_out) {
  const int bid = blockIdx.x;
  const int c = bid & 15;
  const int h = (bid >> 4) & 15;
  const int b = bid >> 8;
  const int tid = threadIdx.x;
  const int w = tid >> 6;
  const int lane = tid & 63;
  const int lg = lane >> 4;
  const int l16 = lane & 15;

  __shared__ __bf16 Ks[64][72];   // K tile row-major [key][d], pad 72
  __shared__ __bf16 Vt[64][72];   // V^T tile [d][key], pad 72

  const int q0 = c * 256 + w * 32;

  // Q fragments (B-operand of swapped QK^T): col q = l16 (+16*qfi), k = ks*32+lg*8+j
  bf16x8 qf[2][2];
#pragma unroll
  for (int qfi = 0; qfi < 2; ++qfi)
#pragma unroll
    for (int ks = 0; ks < 2; ++ks) {
      const int row = q0 + qfi * 16 + l16;
      const int d0 = ks * 32 + lg * 8;
      const float* p = src + ((size_t)(b * 4096 + row) * 1024) + h * 64 + d0;
      bf16x8 v;
#pragma unroll
      for (int j = 0; j < 8; ++j) v[j] = (__bf16)p[j];
      qf[qfi][ks] = v;
    }

  // permuted A-fragment key row for QK^T
  int krow[4];
#pragma unroll
  for (int kf = 0; kf < 4; ++kf)
    krow[kf] = ((kf >> 1) << 5) + ((l16 >> 2) << 3) + ((kf & 1) << 2) + (l16 & 3);

  const f32x4 z4 = {0.f, 0.f, 0.f, 0.f};
  float m_run[2], l_run[2];
  f32x4 o[2][4];  // [qfi][df]: O^T -> row d = df*16+4lg+reg, col q = qfi*16+l16
#pragma unroll
  for (int qfi = 0; qfi < 2; ++qfi) {
    m_run[qfi] = -6.0e8f;
    l_run[qfi] = 0.f;
#pragma unroll
    for (int df = 0; df < 4; ++df) o[qfi][df] = z4;
  }

  const int stage_key = tid >> 3;
  const int stage_d0 = (tid & 7) * 8;

  for (int kt = 0; kt < 12; ++kt) {
    const int kbase = c * 256 - 256 + kt * 64;
    __syncthreads();  // protect K/V LDS from previous iteration's readers
    {
      const int kpos = kbase + stage_key;
      bf16x8 kv;
      if (kpos >= 0 && kpos < 4096) {
        const float* p = src + ((size_t)(b * 4096 + kpos) * 1024) + h * 64 + stage_d0;
#pragma unroll
        for (int j = 0; j < 8; ++j) kv[j] = (__bf16)p[j];
      } else {
#pragma unroll
        for (int j = 0; j < 8; ++j) kv[j] = (__bf16)0.f;
      }
      *(bf16x8*)&Ks[stage_key][stage_d0] = kv;
#pragma unroll
      for (int j = 0; j < 8; ++j) Vt[stage_d0 + j][stage_key] = kv[j];
    }
    __syncthreads();

    const bool skip = (kbase + 63 < 0) | (kbase >= 4096) |
                      (kbase + 63 < q0 - 256) | (kbase > q0 + 31 + 256);
    if (skip) continue;

    // ---- S^T = K_perm Q^T : s[kf][qfi], key = kbase+keymap(kf,4lg+reg) ----
    f32x4 s[4][2];
#pragma unroll
    for (int kf = 0; kf < 4; ++kf)
#pragma unroll
      for (int qfi = 0; qfi < 2; ++qfi) s[kf][qfi] = z4;

#pragma unroll
    for (int ks = 0; ks < 2; ++ks) {
      bf16x8 ka[4];
#pragma unroll
      for (int kf = 0; kf < 4; ++kf)
        ka[kf] = *(const bf16x8*)&Ks[krow[kf]][ks * 32 + lg * 8];
#pragma unroll
      for (int kf = 0; kf < 4; ++kf)
#pragma unroll
        for (int qfi = 0; qfi < 2; ++qfi)
          s[kf][qfi] = MFMA16(ka[kf], qf[qfi][ks], s[kf][qfi]);
    }

    // ---- mask (key = kbase + ks2*32 + 8lg + 4hi + reg, kf = 2ks2+hi) ----
#pragma unroll
    for (int qfi = 0; qfi < 2; ++qfi) {
      const int qp = q0 + qfi * 16 + l16;
#pragma unroll
      for (int kf = 0; kf < 4; ++kf) {
        const int kb0 = kbase + ((kf >> 1) << 5) + 8 * lg + ((kf & 1) << 2);
#pragma unroll
        for (int reg = 0; reg < 4; ++reg) {
          const int kp = kb0 + reg;
          const int rel = kp - qp;
          if (rel > 256 || rel < -256 || kp < 0 || kp >= 4096) s[kf][qfi][reg] = -1e9f;
        }
      }
    }

    // ---- online softmax: per lane, q = l16 (within qfi); 16 local k vals ----
    bf16x4 pb[4][2];
#pragma unroll
    for (int qfi = 0; qfi < 2; ++qfi) {
      float tm = s[0][qfi][0];
#pragma unroll
      for (int kf = 0; kf < 4; ++kf)
#pragma unroll
        for (int reg = 0; reg < 4; ++reg) tm = fmaxf(tm, s[kf][qfi][reg]);
      tm = fmaxf(tm, __shfl_xor(tm, 16, 64));
      tm = fmaxf(tm, __shfl_xor(tm, 32, 64));

      const float mn = fmaxf(m_run[qfi], tm);
      const float scl = __expf(m_run[qfi] - mn);
      m_run[qfi] = mn;

      float rs = 0.f;
#pragma unroll
      for (int kf = 0; kf < 4; ++kf) {
        bf16x4 pv;
#pragma unroll
        for (int reg = 0; reg < 4; ++reg) {
          const float p = __expf(s[kf][qfi][reg] - mn);
          rs += p;
          pv[reg] = (__bf16)p;
        }
        pb[kf][qfi] = pv;
      }
      rs += __shfl_xor(rs, 16, 64);
      rs += __shfl_xor(rs, 32, 64);
      l_run[qfi] = l_run[qfi] * scl + rs;

      // rescale O^T: this lane's column q = l16 -> uniform multiply
#pragma unroll
      for (int df = 0; df < 4; ++df)
#pragma unroll
        for (int reg = 0; reg < 4; ++reg) o[qfi][df][reg] *= scl;
    }

    // ---- O^T += V^T P : A = Vt rows (b128), B = pb concat (registers) ----
#pragma unroll
    for (int ks2 = 0; ks2 < 2; ++ks2) {
      bf16x8 av[4];
#pragma unroll
      for (int df = 0; df < 4; ++df)
        av[df] = *(const bf16x8*)&Vt[df * 16 + l16][ks2 * 32 + lg * 8];
#pragma unroll
      for (int qfi = 0; qfi < 2; ++qfi) {
        const bf16x8 bq = __builtin_shufflevector(pb[2 * ks2][qfi], pb[2 * ks2 + 1][qfi],
                                                  0, 1, 2, 3, 4, 5, 6, 7);
#pragma unroll
        for (int df = 0; df < 4; ++df)
          o[qfi][df] = MFMA16(av[df], bq, o[qfi][df]);
      }
    }
  }

  // epilogue: O /= l ; store O^T -> attn_out[b][q][h*64 + d], float4 per df
#pragma unroll
  for (int qfi = 0; qfi < 2; ++qfi) {
    const float inv = 1.0f / l_run[qfi];
    const int qp = q0 + qfi * 16 + l16;
    float* dst = attn_out + ((size_t)(b * 4096 + qp)) * 1024 + h * 64 + lg * 4;
#pragma unroll
    for (int df = 0; df < 4; ++df) {
      float4 r;
      r.x = o[qfi][df][0] * inv;
      r.y = o[qfi][df][1] * inv;
      r.z = o[qfi][df][2] * inv;
      r.w = o[qfi][df][3] * inv;
      *(float4*)&dst[df * 16] = r;
    }
  }
}

// ---------------------------------------------------------------------------
// 8-phase NT GEMM: BM=256, BN=128, BK=64, 8 waves (4Mx2N), per-wave 64x64.
// 3-deep LDS ring; counted vmcnt(6); T2 swizzle; setprio around MFMA.
// MODE 0: out bf16, +bias, relu.  MODE 1: out f32, +bias.
// ---------------------------------------------------------------------------
template <int MODE>
__global__ __launch_bounds__(512, 2) void gemm8p(const __bf16* __restrict__ A,
                                                 const __bf16* __restrict__ Bt,
                                                 const float* __restrict__ bias,
                                                 void* __restrict__ out,
                                                 int M, int N, int K) {
  __shared__ char smem[147456];  // A ring 3x32KB @0, B ring 3x16KB @98304
  const int tid = threadIdx.x;
  const int w = tid >> 6;
  const int lane = tid & 63;
  const int lg = lane >> 4;
  const int l16 = lane & 15;
  const int wr = w >> 1;
  const int wc = w & 1;

  const int nbn = N >> 7;
  const int x = ((int)blockIdx.x & 7) * ((int)gridDim.x >> 3) + ((int)blockIdx.x >> 3);
  const long bm = (long)(x / nbn) * 256;
  const long bn = (long)(x % nbn) * 128;

  int ao0 = 0, ao1 = 32768, ao2 = 65536;
  int bo0 = 98304, bo1 = 114688, bo2 = 131072;

  const f32x4 z4 = {0.f, 0.f, 0.f, 0.f};
  f32x4 acc[4][4];
#pragma unroll
  for (int i = 0; i < 4; ++i)
#pragma unroll
    for (int j = 0; j < 4; ++j) acc[i][j] = z4;

  const int srow = tid >> 3;
  const int scsw = ((tid & 7) << 4) ^ ((srow & 7) << 4);
  const char* Ag = (const char*)A + ((size_t)(bm + srow) * K) * 2 + scsw;
  const char* Bg = (const char*)Bt + ((size_t)(bn + srow) * K) * 2 + scsw;
  const size_t ustride = (size_t)K * 128;
  char* lw = smem + (w << 10);

  const unsigned asw = (unsigned)((l16 & 7) << 4);
  const int arow = wr * 64 + l16;
  const int brow = wc * 64 + l16;

  auto stA = [&](int kt, int ao, int u) {
    gload_lds16(Ag + (size_t)u * ustride + (size_t)kt * 128, lw + ao + u * 8192);
  };
  auto stB = [&](int kt, int bo, int v) {
    gload_lds16(Bg + (size_t)v * ustride + (size_t)kt * 128, lw + bo + v * 8192);
  };
  auto rdA = [&](int ao, int rf, int ks) {
    return *(const bf16x8*)(smem + ao + (arow + rf * 16) * 128 +
                            ((unsigned)((ks << 6) | (lg << 4)) ^ asw));
  };
  auto rdB = [&](int bo, int cf, int ks) {
    return *(const bf16x8*)(smem + bo + (brow + cf * 16) * 128 +
                            ((unsigned)((ks << 6) | (lg << 4)) ^ asw));
  };

  const int NT = K >> 6;

#pragma unroll
  for (int u = 0; u < 4; ++u) stA(0, ao0, u);
  stB(0, bo0, 0); stB(0, bo0, 1);
#pragma unroll
  for (int u = 0; u < 4; ++u) stA(1, ao1, u);
  stB(1, bo1, 0); stB(1, bo1, 1);
  asm volatile("s_waitcnt vmcnt(6)" ::: "memory");
  __builtin_amdgcn_s_barrier();

  for (int t = 0; t < NT; ++t) {
    const bool st = (t + 2) < NT;
    const int kt2 = t + 2;
    bf16x8 af[2][2], bl[2][2], bh[2][2];

#pragma unroll
    for (int i = 0; i < 2; ++i)
#pragma unroll
      for (int ks = 0; ks < 2; ++ks) af[i][ks] = rdA(ao0, i, ks);
#pragma unroll
    for (int j = 0; j < 2; ++j)
#pragma unroll
      for (int ks = 0; ks < 2; ++ks) bl[j][ks] = rdB(bo0, j, ks);
    if (st) { stA(kt2, ao2, 0); stA(kt2, ao2, 1); }
    __builtin_amdgcn_s_barrier();
    asm volatile("s_waitcnt lgkmcnt(0)" ::: "memory");
    __builtin_amdgcn_s_setprio(1);
#pragma unroll
    for (int i = 0; i < 2; ++i)
#pragma unroll
      for (int j = 0; j < 2; ++j)
#pragma unroll
        for (int ks = 0; ks < 2; ++ks)
          acc[i][j] = MFMA16(af[i][ks], bl[j][ks], acc[i][j]);
    __builtin_amdgcn_s_setprio(0);
    __builtin_amdgcn_s_barrier();

#pragma unroll
    for (int j = 0; j < 2; ++j)
#pragma unroll
      for (int ks = 0; ks < 2; ++ks) bh[j][ks] = rdB(bo0, 2 + j, ks);
    if (st) { stA(kt2, ao2, 2); stA(kt2, ao2, 3); }
    __builtin_amdgcn_s_barrier();
    asm volatile("s_waitcnt lgkmcnt(0)" ::: "memory");
    __builtin_amdgcn_s_setprio(1);
#pragma unroll
    for (int i = 0; i < 2; ++i)
#pragma unroll
      for (int j = 0; j < 2; ++j)
#pragma unroll
        for (int ks = 0; ks < 2; ++ks)
          acc[i][2 + j] = MFMA16(af[i][ks], bh[j][ks], acc[i][2 + j]);
    __builtin_amdgcn_s_setprio(0);
    __builtin_amdgcn_s_barrier();

#pragma unroll
    for (int i = 0; i < 2; ++i)
#pragma unroll
      for (int ks = 0; ks < 2; ++ks) af[i][ks] = rdA(ao0, 2 + i, ks);
    if (st) stB(kt2, bo2, 0);
    __builtin_amdgcn_s_barrier();
    asm volatile("s_waitcnt lgkmcnt(0)" ::: "memory");
    __builtin_amdgcn_s_setprio(1);
#pragma unroll
    for (int i = 0; i < 2; ++i)
#pragma unroll
      for (int j = 0; j < 2; ++j)
#pragma unroll
        for (int ks = 0; ks < 2; ++ks)
          acc[2 + i][j] = MFMA16(af[i][ks], bl[j][ks], acc[2 + i][j]);
    __builtin_amdgcn_s_setprio(0);
    __builtin_amdgcn_s_barrier();

    if (st) stB(kt2, bo2, 1);
    asm volatile("s_waitcnt vmcnt(6)" ::: "memory");
    __builtin_amdgcn_s_barrier();
    __builtin_amdgcn_s_setprio(1);
#pragma unroll
    for (int i = 0; i < 2; ++i)
#pragma unroll
      for (int j = 0; j < 2; ++j)
#pragma unroll
        for (int ks = 0; ks < 2; ++ks)
          acc[2 + i][2 + j] = MFMA16(af[i][ks], bh[j][ks], acc[2 + i][2 + j]);
    __builtin_amdgcn_s_setprio(0);
    __builtin_amdgcn_s_barrier();

    const int ta = ao0; ao0 = ao1; ao1 = ao2; ao2 = ta;
    const int tb = bo0; bo0 = bo1; bo1 = bo2; bo2 = tb;
  }

  float bv[4];
#pragma unroll
  for (int cf = 0; cf < 4; ++cf) bv[cf] = bias[bn + wc * 64 + cf * 16 + l16];
#pragma unroll
  for (int rf = 0; rf < 4; ++rf)
#pragma unroll
    for (int reg = 0; reg < 4; ++reg) {
      const long row = bm + wr * 64 + rf * 16 + lg * 4 + reg;
#pragma unroll
      for (int cf = 0; cf < 4; ++cf) {
        const long col = bn + wc * 64 + cf * 16 + l16;
        float v = acc[rf][cf][reg] + bv[cf];
        if (MODE == 0) {
          ((__bf16*)out)[row * N + col] = (__bf16)fmaxf(v, 0.f);
        } else {
          ((float*)out)[row * N + col] = v;
        }
      }
    }
}

// ---------------------------------------------------------------------------
__global__ __launch_bounds__(256) void transpose_cvt(const float* __restrict__ in,
                                                     __bf16* __restrict__ out,
                                                     int R, int C) {
  __shared__ float tile[64][65];
  const long r0 = (long)blockIdx.y * 64;
  const long c0 = (long)blockIdx.x * 64;
  const int t = threadIdx.x;
  const int tr = t >> 6;
  const int tc = t & 63;
#pragma unroll
  for (int i = 0; i < 16; ++i) {
    const int r = tr * 16 + i;
    tile[r][tc] = in[(r0 + r) * C + c0 + tc];
  }
  __syncthreads();
#pragma unroll
  for (int i = 0; i < 16; ++i) {
    const int cc = tr * 16 + i;
    out[(c0 + cc) * (long)R + r0 + tc] = (__bf16)tile[tc][cc];
  }
}

// ---------------------------------------------------------------------------
__global__ __launch_bounds__(256) void ln1_kernel(const float* __restrict__ src,
                                                  const float* __restrict__ attn,
                                                  const float* __restrict__ g,
                                                  const float* __restrict__ bta,
                                                  __bf16* __restrict__ xb) {
  const long r = blockIdx.x;
  const int t = threadIdx.x;
  const float4 a = *(const float4*)&src[r * 1024 + t * 4];
  const float4 cc = *(const float4*)&attn[r * 1024 + t * 4];
  float v[4] = {a.x + cc.x, a.y + cc.y, a.z + cc.z, a.w + cc.w};
  float s = v[0] + v[1] + v[2] + v[3];
  float s2 = v[0] * v[0] + v[1] * v[1] + v[2] * v[2] + v[3] * v[3];
#pragma unroll
  for (int off = 32; off >= 1; off >>= 1) {
    s += __shfl_xor(s, off, 64);
    s2 += __shfl_xor(s2, off, 64);
  }
  __shared__ float red[8];
  if ((t & 63) == 0) { red[t >> 6] = s; red[(t >> 6) + 4] = s2; }
  __syncthreads();
  s = red[0] + red[1] + red[2] + red[3];
  s2 = red[4] + red[5] + red[6] + red[7];
  const float mu = s * (1.f / 1024.f);
  const float var = s2 * (1.f / 1024.f) - mu * mu;
  const float rstd = rsqrtf(var + 1e-5f);
  const float4 gv = *(const float4*)&g[t * 4];
  const float4 bv = *(const float4*)&bta[t * 4];
  bf16x4 y;
  y[0] = (__bf16)((v[0] - mu) * rstd * gv.x + bv.x);
  y[1] = (__bf16)((v[1] - mu) * rstd * gv.y + bv.y);
  y[2] = (__bf16)((v[2] - mu) * rstd * gv.z + bv.z);
  y[3] = (__bf16)((v[3] - mu) * rstd * gv.w + bv.w);
  *(bf16x4*)&xb[r * 1024 + t * 4] = y;
}

__global__ __launch_bounds__(256) void ln2_kernel(const __bf16* __restrict__ xb,
                                                  const float* __restrict__ ff,
                                                  const float* __restrict__ g,
                                                  const float* __restrict__ bta,
                                                  float* __restrict__ out) {
  const long r = blockIdx.x;
  const int t = threadIdx.x;
  const bf16x4 xv = *(const bf16x4*)&xb[r * 1024 + t * 4];
  const float4 fv = *(const float4*)&ff[r * 1024 + t * 4];
  float v[4] = {(float)xv[0] + fv.x, (float)xv[1] + fv.y,
                (float)xv[2] + fv.z, (float)xv[3] + fv.w};
  float s = v[0] + v[1] + v[2] + v[3];
  float s2 = v[0] * v[0] + v[1] * v[1] + v[2] * v[2] + v[3] * v[3];
#pragma unroll
  for (int off = 32; off >= 1; off >>= 1) {
    s += __shfl_xor(s, off, 64);
    s2 += __shfl_xor(s2, off, 64);
  }
  __shared__ float red[8];
  if ((t & 63) == 0) { red[t >> 6] = s; red[(t >> 6) + 4] = s2; }
  __syncthreads();
  s = red[0] + red[1] + red[2] + red[3];
  s2 = red[4] + red[5] + red[6] + red[7];
  const float mu = s * (1.f / 1024.f);
  const float var = s2 * (1.f / 1024.f) - mu * mu;
  const float rstd = rsqrtf(var + 1e-5f);
  const float4 gv = *(const float4*)&g[t * 4];
  const float4 bv = *(const float4*)&bta[t * 4];
  float4 y;
  y.x = (v[0] - mu) * rstd * gv.x + bv.x;
  y.y = (v[1] - mu) * rstd * gv.y + bv.y;
  y.z = (v[2] - mu) * rstd * gv.z + bv.z;
  y.w = (v[3] - mu) * rstd * gv.w + bv.w;
  *(float4*)&out[r * 1024 + t * 4] = y;
}

// ---------------------------------------------------------------------------
extern "C" void kernel_launch(void* const* d_in, const int* in_sizes, int n_in,
                              void* d_out, int out_size, void* d_ws, size_t ws_size,
                              hipStream_t stream) {
  const float* src = (const float*)d_in[0];
  const float* ln1_g = (const float*)d_in[1];
  const float* ln1_b = (const float*)d_in[2];
  const float* ln2_g = (const float*)d_in[3];
  const float* ln2_b = (const float*)d_in[4];
  const float* W1 = (const float*)d_in[5];
  const float* b1 = (const float*)d_in[6];
  const float* W2 = (const float*)d_in[7];
  const float* b2 = (const float*)d_in[8];
  float* out = (float*)d_out;
  char* ws = (char*)d_ws;

  float* attn_ff = (float*)ws;                                  // 32 MB (attn, then ff)
  __bf16* xb = (__bf16*)(ws + 33554432);                        // 16 MB
  __bf16* w1t = (__bf16*)(ws + 33554432 + 16777216);            // 8 MB
  __bf16* w2t = (__bf16*)(ws + 33554432 + 16777216 + 8388608);  // 8 MB
  __bf16* hbuf = (__bf16*)(ws + 67108864);                      // Mc*4096*2 B

  int Mc = 8192;
  while (Mc > 512 && (67108864ull + (size_t)Mc * 8192ull) > ws_size) Mc >>= 1;

  transpose_cvt<<<dim3(4096 / 64, 1024 / 64), 256, 0, stream>>>(W1, w1t, 1024, 4096);
  transpose_cvt<<<dim3(1024 / 64, 4096 / 64), 256, 0, stream>>>(W2, w2t, 4096, 1024);
  attn_kernel<<<512, 512, 0, stream>>>(src, attn_ff);
  ln1_kernel<<<8192, 256, 0, stream>>>(src, attn_ff, ln1_g, ln1_b, xb);
  for (int m0 = 0; m0 < 8192; m0 += Mc) {
    gemm8p<0><<<(Mc / 256) * (4096 / 128), 512, 0, stream>>>(
        xb + (size_t)m0 * 1024, w1t, b1, hbuf, Mc, 4096, 1024);
    gemm8p<1><<<(Mc / 256) * (1024 / 128), 512, 0, stream>>>(
        hbuf, w2t, b2, attn_ff + (size_t)m0 * 1024, Mc, 1024, 4096);
  }
  ln2_kernel<<<8192, 256, 0, stream>>>(xb, attn_ff, ln2_g, ln2_b, out);
}

// Round 5
// 256.205 us; speedup vs baseline: 1.2467x; 1.0605x over previous
//
#include <hip/hip_runtime.h>

typedef __bf16 bf16x8 __attribute__((ext_vector_type(8)));
typedef __bf16 bf16x4 __attribute__((ext_vector_type(4)));
typedef float f32x4 __attribute__((ext_vector_type(4)));

#define MFMA16(a, b, c) __builtin_amdgcn_mfma_f32_16x16x32_bf16((a), (b), (c), 0, 0, 0)

__device__ __forceinline__ void gload_lds16(const void* g, void* l) {
  __builtin_amdgcn_global_load_lds(
      (const __attribute__((address_space(1))) unsigned int*)g,
      (__attribute__((address_space(3))) unsigned int*)l, 16, 0, 0);
}

// ---------------------------------------------------------------------------
// Sliding-window attention, permuted-fragment swapped structure (round 4,
// passing — unchanged).
// ---------------------------------------------------------------------------
__global__ __launch_bounds__(512, 2) void attn_kernel(const float* __restrict__ src,
                                                      float* __restrict__ attn_out) {
  const int bid = blockIdx.x;
  const int c = bid & 15;
  const int h = (bid >> 4) & 15;
  const int b = bid >> 8;
  const int tid = threadIdx.x;
  const int w = tid >> 6;
  const int lane = tid & 63;
  const int lg = lane >> 4;
  const int l16 = lane & 15;

  __shared__ __bf16 Ks[64][72];   // K tile row-major [key][d], pad 72
  __shared__ __bf16 Vt[64][72];   // V^T tile [d][key], pad 72

  const int q0 = c * 256 + w * 32;

  bf16x8 qf[2][2];
#pragma unroll
  for (int qfi = 0; qfi < 2; ++qfi)
#pragma unroll
    for (int ks = 0; ks < 2; ++ks) {
      const int row = q0 + qfi * 16 + l16;
      const int d0 = ks * 32 + lg * 8;
      const float* p = src + ((size_t)(b * 4096 + row) * 1024) + h * 64 + d0;
      bf16x8 v;
#pragma unroll
      for (int j = 0; j < 8; ++j) v[j] = (__bf16)p[j];
      qf[qfi][ks] = v;
    }

  int krow[4];
#pragma unroll
  for (int kf = 0; kf < 4; ++kf)
    krow[kf] = ((kf >> 1) << 5) + ((l16 >> 2) << 3) + ((kf & 1) << 2) + (l16 & 3);

  const f32x4 z4 = {0.f, 0.f, 0.f, 0.f};
  float m_run[2], l_run[2];
  f32x4 o[2][4];
#pragma unroll
  for (int qfi = 0; qfi < 2; ++qfi) {
    m_run[qfi] = -6.0e8f;
    l_run[qfi] = 0.f;
#pragma unroll
    for (int df = 0; df < 4; ++df) o[qfi][df] = z4;
  }

  const int stage_key = tid >> 3;
  const int stage_d0 = (tid & 7) * 8;

  for (int kt = 0; kt < 12; ++kt) {
    const int kbase = c * 256 - 256 + kt * 64;
    __syncthreads();
    {
      const int kpos = kbase + stage_key;
      bf16x8 kv;
      if (kpos >= 0 && kpos < 4096) {
        const float* p = src + ((size_t)(b * 4096 + kpos) * 1024) + h * 64 + stage_d0;
#pragma unroll
        for (int j = 0; j < 8; ++j) kv[j] = (__bf16)p[j];
      } else {
#pragma unroll
        for (int j = 0; j < 8; ++j) kv[j] = (__bf16)0.f;
      }
      *(bf16x8*)&Ks[stage_key][stage_d0] = kv;
#pragma unroll
      for (int j = 0; j < 8; ++j) Vt[stage_d0 + j][stage_key] = kv[j];
    }
    __syncthreads();

    const bool skip = (kbase + 63 < 0) | (kbase >= 4096) |
                      (kbase + 63 < q0 - 256) | (kbase > q0 + 31 + 256);
    if (skip) continue;

    f32x4 s[4][2];
#pragma unroll
    for (int kf = 0; kf < 4; ++kf)
#pragma unroll
      for (int qfi = 0; qfi < 2; ++qfi) s[kf][qfi] = z4;

#pragma unroll
    for (int ks = 0; ks < 2; ++ks) {
      bf16x8 ka[4];
#pragma unroll
      for (int kf = 0; kf < 4; ++kf)
        ka[kf] = *(const bf16x8*)&Ks[krow[kf]][ks * 32 + lg * 8];
#pragma unroll
      for (int kf = 0; kf < 4; ++kf)
#pragma unroll
        for (int qfi = 0; qfi < 2; ++qfi)
          s[kf][qfi] = MFMA16(ka[kf], qf[qfi][ks], s[kf][qfi]);
    }

#pragma unroll
    for (int qfi = 0; qfi < 2; ++qfi) {
      const int qp = q0 + qfi * 16 + l16;
#pragma unroll
      for (int kf = 0; kf < 4; ++kf) {
        const int kb0 = kbase + ((kf >> 1) << 5) + 8 * lg + ((kf & 1) << 2);
#pragma unroll
        for (int reg = 0; reg < 4; ++reg) {
          const int kp = kb0 + reg;
          const int rel = kp - qp;
          if (rel > 256 || rel < -256 || kp < 0 || kp >= 4096) s[kf][qfi][reg] = -1e9f;
        }
      }
    }

    bf16x4 pb[4][2];
#pragma unroll
    for (int qfi = 0; qfi < 2; ++qfi) {
      float tm = s[0][qfi][0];
#pragma unroll
      for (int kf = 0; kf < 4; ++kf)
#pragma unroll
        for (int reg = 0; reg < 4; ++reg) tm = fmaxf(tm, s[kf][qfi][reg]);
      tm = fmaxf(tm, __shfl_xor(tm, 16, 64));
      tm = fmaxf(tm, __shfl_xor(tm, 32, 64));

      const float mn = fmaxf(m_run[qfi], tm);
      const float scl = __expf(m_run[qfi] - mn);
      m_run[qfi] = mn;

      float rs = 0.f;
#pragma unroll
      for (int kf = 0; kf < 4; ++kf) {
        bf16x4 pv;
#pragma unroll
        for (int reg = 0; reg < 4; ++reg) {
          const float p = __expf(s[kf][qfi][reg] - mn);
          rs += p;
          pv[reg] = (__bf16)p;
        }
        pb[kf][qfi] = pv;
      }
      rs += __shfl_xor(rs, 16, 64);
      rs += __shfl_xor(rs, 32, 64);
      l_run[qfi] = l_run[qfi] * scl + rs;

#pragma unroll
      for (int df = 0; df < 4; ++df)
#pragma unroll
        for (int reg = 0; reg < 4; ++reg) o[qfi][df][reg] *= scl;
    }

#pragma unroll
    for (int ks2 = 0; ks2 < 2; ++ks2) {
      bf16x8 av[4];
#pragma unroll
      for (int df = 0; df < 4; ++df)
        av[df] = *(const bf16x8*)&Vt[df * 16 + l16][ks2 * 32 + lg * 8];
#pragma unroll
      for (int qfi = 0; qfi < 2; ++qfi) {
        const bf16x8 bq = __builtin_shufflevector(pb[2 * ks2][qfi], pb[2 * ks2 + 1][qfi],
                                                  0, 1, 2, 3, 4, 5, 6, 7);
#pragma unroll
        for (int df = 0; df < 4; ++df)
          o[qfi][df] = MFMA16(av[df], bq, o[qfi][df]);
      }
    }
  }

#pragma unroll
  for (int qfi = 0; qfi < 2; ++qfi) {
    const float inv = 1.0f / l_run[qfi];
    const int qp = q0 + qfi * 16 + l16;
    float* dst = attn_out + ((size_t)(b * 4096 + qp)) * 1024 + h * 64 + lg * 4;
#pragma unroll
    for (int df = 0; df < 4; ++df) {
      float4 r;
      r.x = o[qfi][df][0] * inv;
      r.y = o[qfi][df][1] * inv;
      r.z = o[qfi][df][2] * inv;
      r.w = o[qfi][df][3] * inv;
      *(float4*)&dst[df * 16] = r;
    }
  }
}

// ---------------------------------------------------------------------------
// 8-phase-style NT GEMM, m201 geometry: BM=BN=256, BK=64, 8 waves (2M x 4N),
// per-wave 128x64, 4 phases x 16 MFMA per K-tile. 2-buffer LDS (128 KiB),
// K-half staging granularity (Aklo/Bklo/Akhi/Bkhi, 2 gloads/thread each),
// counted vmcnt(4) at phase-1/phase-3 ends (never 0 except final tile).
// LDS layout per buffer: [ks][256 rows][32 k] with slot-XOR swizzle
// slot = lg ^ ((row>>1)&3) applied to BOTH staging source and ds_read.
// MODE 0: out bf16, +bias, relu.  MODE 1: out f32 (no bias), split-K via
// blockIdx.y -> out0/out1.
// ---------------------------------------------------------------------------
template <int MODE>
__global__ __launch_bounds__(512, 2) void gemm8p(const __bf16* __restrict__ A,
                                                 const __bf16* __restrict__ Bt,
                                                 const float* __restrict__ bias,
                                                 void* __restrict__ out0,
                                                 void* __restrict__ out1,
                                                 int M, int N, int Kstride, int Klen) {
  __shared__ char smem[131072];  // A: [0,64K) two 32K bufs; B: [64K,128K)
  const int tid = threadIdx.x;
  const int w = tid >> 6;
  const int lane = tid & 63;
  const int lg = lane >> 4;
  const int l16 = lane & 15;
  const int wr = w >> 2;  // 0..1 -> 128-row half
  const int wc = w & 3;   // 0..3 -> 64-col quarter

  const int nbn = N >> 8;
  const int x = ((int)blockIdx.x & 7) * ((int)gridDim.x >> 3) + ((int)blockIdx.x >> 3);
  const long bm = (long)(x / nbn) * 256;
  const long bn = (long)(x % nbn) * 256;
  const long koff = (long)blockIdx.y * Klen;
  void* out = blockIdx.y ? out1 : out0;

  const f32x4 z4 = {0.f, 0.f, 0.f, 0.f};
  f32x4 acc[8][4];
#pragma unroll
  for (int i = 0; i < 8; ++i)
#pragma unroll
    for (int j = 0; j < 4; ++j) acc[i][j] = z4;

  // staging addressing: thread covers (row = u*128 + tid>>2, slot = tid&3),
  // stored k-group g = slot ^ ((row>>1)&3) = (tid&3) ^ ((tid>>3)&3)
  const int srow = tid >> 2;
  const int g0 = (tid & 3) ^ ((tid >> 3) & 3);
  const __bf16* Ag = A + (size_t)(bm + srow) * Kstride + koff + g0 * 8;
  const __bf16* Bg = Bt + (size_t)(bn + srow) * Kstride + koff + g0 * 8;

  auto stage = [&](int kt, int osel, int isB, int khalf) {
    const __bf16* src = (isB ? Bg : Ag) + (size_t)kt * 64 + khalf * 32;
    char* dst = smem + (isB ? 65536 : 0) + osel * 32768 + khalf * 16384 + (w << 10);
    gload_lds16(src, dst);
    gload_lds16(src + (size_t)128 * Kstride, dst + 8192);
  };

  // fragment reads: addr = buf + ks*16384 + row*64 + (lg ^ ((l16>>1)&3))*16
  const int lslot = (lg ^ ((l16 >> 1) & 3)) << 4;
  const char* pA = smem + (wr * 128 + l16) * 64 + lslot;
  const char* pB = smem + 65536 + (wc * 64 + l16) * 64 + lslot;
  auto rdA = [&](int sel, int rf, int ks) {
    return *(const bf16x8*)(pA + sel * 32768 + ks * 16384 + rf * 1024);
  };
  auto rdB = [&](int sel, int cf, int ks) {
    return *(const bf16x8*)(pB + sel * 32768 + ks * 16384 + cf * 1024);
  };

  const int NT = Klen >> 6;

  // prologue: stage tile 0 (Aklo, Bklo, Akhi, Bkhi = 8 loads/thread)
  stage(0, 0, 0, 0);
  stage(0, 0, 1, 0);
  stage(0, 0, 0, 1);
  stage(0, 0, 1, 1);
  asm volatile("s_waitcnt vmcnt(4)" ::: "memory");  // klo(0) landed
  __builtin_amdgcn_s_barrier();

  for (int t = 0; t < NT; ++t) {
    const int sel = t & 1, osel = sel ^ 1;
    const bool st = (t + 1) < NT;
    const int kt1 = t + 1;
    bf16x8 af[8], b0, b1;

    // ---- phase 0: A ks0 (8 rd) + B cf0-1 ks0 (2 rd); stage Aklo(t+1) ----
#pragma unroll
    for (int rf = 0; rf < 8; ++rf) af[rf] = rdA(sel, rf, 0);
    b0 = rdB(sel, 0, 0);
    b1 = rdB(sel, 1, 0);
    if (st) stage(kt1, osel, 0, 0);
    __builtin_amdgcn_s_barrier();
    asm volatile("s_waitcnt lgkmcnt(0)" ::: "memory");
    __builtin_amdgcn_s_setprio(1);
#pragma unroll
    for (int rf = 0; rf < 8; ++rf) {
      acc[rf][0] = MFMA16(af[rf], b0, acc[rf][0]);
      acc[rf][1] = MFMA16(af[rf], b1, acc[rf][1]);
    }
    __builtin_amdgcn_s_setprio(0);
    __builtin_amdgcn_s_barrier();

    // ---- phase 1: B cf2-3 ks0 (2 rd); stage Bklo(t+1); vmcnt -> khi(t) ----
    b0 = rdB(sel, 2, 0);
    b1 = rdB(sel, 3, 0);
    if (st) stage(kt1, osel, 1, 0);
    __builtin_amdgcn_s_barrier();
    asm volatile("s_waitcnt lgkmcnt(0)" ::: "memory");
    __builtin_amdgcn_s_setprio(1);
#pragma unroll
    for (int rf = 0; rf < 8; ++rf) {
      acc[rf][2] = MFMA16(af[rf], b0, acc[rf][2]);
      acc[rf][3] = MFMA16(af[rf], b1, acc[rf][3]);
    }
    __builtin_amdgcn_s_setprio(0);
    if (st) asm volatile("s_waitcnt vmcnt(4)" ::: "memory");
    else    asm volatile("s_waitcnt vmcnt(0)" ::: "memory");
    __builtin_amdgcn_s_barrier();

    // ---- phase 2: A ks1 (8 rd) + B cf0-1 ks1 (2 rd); stage Akhi(t+1) ----
#pragma unroll
    for (int rf = 0; rf < 8; ++rf) af[rf] = rdA(sel, rf, 1);
    b0 = rdB(sel, 0, 1);
    b1 = rdB(sel, 1, 1);
    if (st) stage(kt1, osel, 0, 1);
    __builtin_amdgcn_s_barrier();
    asm volatile("s_waitcnt lgkmcnt(0)" ::: "memory");
    __builtin_amdgcn_s_setprio(1);
#pragma unroll
    for (int rf = 0; rf < 8; ++rf) {
      acc[rf][0] = MFMA16(af[rf], b0, acc[rf][0]);
      acc[rf][1] = MFMA16(af[rf], b1, acc[rf][1]);
    }
    __builtin_amdgcn_s_setprio(0);
    __builtin_amdgcn_s_barrier();

    // ---- phase 3: B cf2-3 ks1 (2 rd); stage Bkhi(t+1); vmcnt -> klo(t+1) ----
    b0 = rdB(sel, 2, 1);
    b1 = rdB(sel, 3, 1);
    if (st) stage(kt1, osel, 1, 1);
    __builtin_amdgcn_s_barrier();
    asm volatile("s_waitcnt lgkmcnt(0)" ::: "memory");
    __builtin_amdgcn_s_setprio(1);
#pragma unroll
    for (int rf = 0; rf < 8; ++rf) {
      acc[rf][2] = MFMA16(af[rf], b0, acc[rf][2]);
      acc[rf][3] = MFMA16(af[rf], b1, acc[rf][3]);
    }
    __builtin_amdgcn_s_setprio(0);
    if (st) asm volatile("s_waitcnt vmcnt(4)" ::: "memory");
    __builtin_amdgcn_s_barrier();
  }

  float bv[4];
  if (MODE == 0) {
#pragma unroll
    for (int cf = 0; cf < 4; ++cf) bv[cf] = bias[bn + wc * 64 + cf * 16 + l16];
  }
#pragma unroll
  for (int rf = 0; rf < 8; ++rf)
#pragma unroll
    for (int reg = 0; reg < 4; ++reg) {
      const long row = bm + wr * 128 + rf * 16 + lg * 4 + reg;
#pragma unroll
      for (int cf = 0; cf < 4; ++cf) {
        const long col = bn + wc * 64 + cf * 16 + l16;
        if (MODE == 0) {
          const float v = fmaxf(acc[rf][cf][reg] + bv[cf], 0.f);
          ((__bf16*)out)[row * N + col] = (__bf16)v;
        } else {
          ((float*)out)[row * N + col] = acc[rf][cf][reg];
        }
      }
    }
}

// ---------------------------------------------------------------------------
__global__ __launch_bounds__(256) void transpose_cvt(const float* __restrict__ in,
                                                     __bf16* __restrict__ out,
                                                     int R, int C) {
  __shared__ float tile[64][65];
  const long r0 = (long)blockIdx.y * 64;
  const long c0 = (long)blockIdx.x * 64;
  const int t = threadIdx.x;
  const int tr = t >> 6;
  const int tc = t & 63;
#pragma unroll
  for (int i = 0; i < 16; ++i) {
    const int r = tr * 16 + i;
    tile[r][tc] = in[(r0 + r) * C + c0 + tc];
  }
  __syncthreads();
#pragma unroll
  for (int i = 0; i < 16; ++i) {
    const int cc = tr * 16 + i;
    out[(c0 + cc) * (long)R + r0 + tc] = (__bf16)tile[tc][cc];
  }
}

// ---------------------------------------------------------------------------
__global__ __launch_bounds__(256) void ln1_kernel(const float* __restrict__ src,
                                                  const float* __restrict__ attn,
                                                  const float* __restrict__ g,
                                                  const float* __restrict__ bta,
                                                  __bf16* __restrict__ xb) {
  const long r = blockIdx.x;
  const int t = threadIdx.x;
  const float4 a = *(const float4*)&src[r * 1024 + t * 4];
  const float4 cc = *(const float4*)&attn[r * 1024 + t * 4];
  float v[4] = {a.x + cc.x, a.y + cc.y, a.z + cc.z, a.w + cc.w};
  float s = v[0] + v[1] + v[2] + v[3];
  float s2 = v[0] * v[0] + v[1] * v[1] + v[2] * v[2] + v[3] * v[3];
#pragma unroll
  for (int off = 32; off >= 1; off >>= 1) {
    s += __shfl_xor(s, off, 64);
    s2 += __shfl_xor(s2, off, 64);
  }
  __shared__ float red[8];
  if ((t & 63) == 0) { red[t >> 6] = s; red[(t >> 6) + 4] = s2; }
  __syncthreads();
  s = red[0] + red[1] + red[2] + red[3];
  s2 = red[4] + red[5] + red[6] + red[7];
  const float mu = s * (1.f / 1024.f);
  const float var = s2 * (1.f / 1024.f) - mu * mu;
  const float rstd = rsqrtf(var + 1e-5f);
  const float4 gv = *(const float4*)&g[t * 4];
  const float4 bv = *(const float4*)&bta[t * 4];
  bf16x4 y;
  y[0] = (__bf16)((v[0] - mu) * rstd * gv.x + bv.x);
  y[1] = (__bf16)((v[1] - mu) * rstd * gv.y + bv.y);
  y[2] = (__bf16)((v[2] - mu) * rstd * gv.z + bv.z);
  y[3] = (__bf16)((v[3] - mu) * rstd * gv.w + bv.w);
  *(bf16x4*)&xb[r * 1024 + t * 4] = y;
}

__global__ __launch_bounds__(256) void ln2_kernel(const __bf16* __restrict__ xb,
                                                  const float* __restrict__ f0,
                                                  const float* __restrict__ f1,
                                                  const float* __restrict__ b2,
                                                  const float* __restrict__ g,
                                                  const float* __restrict__ bta,
                                                  float* __restrict__ out) {
  const long r = blockIdx.x;
  const int t = threadIdx.x;
  const bf16x4 xv = *(const bf16x4*)&xb[r * 1024 + t * 4];
  const float4 f0v = *(const float4*)&f0[r * 1024 + t * 4];
  const float4 f1v = *(const float4*)&f1[r * 1024 + t * 4];
  const float4 b2v = *(const float4*)&b2[t * 4];
  float v[4] = {(float)xv[0] + f0v.x + f1v.x + b2v.x,
                (float)xv[1] + f0v.y + f1v.y + b2v.y,
                (float)xv[2] + f0v.z + f1v.z + b2v.z,
                (float)xv[3] + f0v.w + f1v.w + b2v.w};
  float s = v[0] + v[1] + v[2] + v[3];
  float s2 = v[0] * v[0] + v[1] * v[1] + v[2] * v[2] + v[3] * v[3];
#pragma unroll
  for (int off = 32; off >= 1; off >>= 1) {
    s += __shfl_xor(s, off, 64);
    s2 += __shfl_xor(s2, off, 64);
  }
  __shared__ float red[8];
  if ((t & 63) == 0) { red[t >> 6] = s; red[(t >> 6) + 4] = s2; }
  __syncthreads();
  s = red[0] + red[1] + red[2] + red[3];
  s2 = red[4] + red[5] + red[6] + red[7];
  const float mu = s * (1.f / 1024.f);
  const float var = s2 * (1.f / 1024.f) - mu * mu;
  const float rstd = rsqrtf(var + 1e-5f);
  const float4 gv = *(const float4*)&g[t * 4];
  const float4 bv = *(const float4*)&bta[t * 4];
  float4 y;
  y.x = (v[0] - mu) * rstd * gv.x + bv.x;
  y.y = (v[1] - mu) * rstd * gv.y + bv.y;
  y.z = (v[2] - mu) * rstd * gv.z + bv.z;
  y.w = (v[3] - mu) * rstd * gv.w + bv.w;
  *(float4*)&out[r * 1024 + t * 4] = y;
}

// ---------------------------------------------------------------------------
extern "C" void kernel_launch(void* const* d_in, const int* in_sizes, int n_in,
                              void* d_out, int out_size, void* d_ws, size_t ws_size,
                              hipStream_t stream) {
  const float* src = (const float*)d_in[0];
  const float* ln1_g = (const float*)d_in[1];
  const float* ln1_b = (const float*)d_in[2];
  const float* ln2_g = (const float*)d_in[3];
  const float* ln2_b = (const float*)d_in[4];
  const float* W1 = (const float*)d_in[5];
  const float* b1 = (const float*)d_in[6];
  const float* W2 = (const float*)d_in[7];
  const float* b2 = (const float*)d_in[8];
  float* out = (float*)d_out;
  char* ws = (char*)d_ws;

  const size_t MB = 1048576;
  float* ff0 = (float*)ws;                  // 32 MB (attn out, then FF half 0)
  float* ff1 = (float*)(ws + 32 * MB);      // 32 MB (FF half 1)
  __bf16* xb = (__bf16*)(ws + 64 * MB);     // 16 MB
  __bf16* w1t = (__bf16*)(ws + 80 * MB);    // 8 MB
  __bf16* w2t = (__bf16*)(ws + 88 * MB);    // 8 MB
  __bf16* hbuf = (__bf16*)(ws + 96 * MB);   // Mc*4096*2 B

  int Mc = 8192;
  while (Mc > 512 && 96 * MB + (size_t)Mc * 8192 > ws_size) Mc >>= 1;

  transpose_cvt<<<dim3(4096 / 64, 1024 / 64), 256, 0, stream>>>(W1, w1t, 1024, 4096);
  transpose_cvt<<<dim3(1024 / 64, 4096 / 64), 256, 0, stream>>>(W2, w2t, 4096, 1024);
  attn_kernel<<<512, 512, 0, stream>>>(src, ff0);
  ln1_kernel<<<8192, 256, 0, stream>>>(src, ff0, ln1_g, ln1_b, xb);
  for (int m0 = 0; m0 < 8192; m0 += Mc) {
    gemm8p<0><<<dim3((Mc / 256) * (4096 / 256), 1), 512, 0, stream>>>(
        xb + (size_t)m0 * 1024, w1t, b1, hbuf, hbuf, Mc, 4096, 1024, 1024);
    gemm8p<1><<<dim3((Mc / 256) * (1024 / 256), 2), 512, 0, stream>>>(
        hbuf, w2t, nullptr, ff0 + (size_t)m0 * 1024, ff1 + (size_t)m0 * 1024,
        Mc, 1024, 4096, 2048);
  }
  ln2_kernel<<<8192, 256, 0, stream>>>(xb, ff0, ff1, b2, ln2_g, ln2_b, out);
}

// Round 6
// 253.325 us; speedup vs baseline: 1.2609x; 1.0114x over previous
//
#include <hip/hip_runtime.h>

typedef __bf16 bf16x8 __attribute__((ext_vector_type(8)));
typedef __bf16 bf16x4 __attribute__((ext_vector_type(4)));
typedef float f32x4 __attribute__((ext_vector_type(4)));

#define MFMA16(a, b, c) __builtin_amdgcn_mfma_f32_16x16x32_bf16((a), (b), (c), 0, 0, 0)

__device__ __forceinline__ void gload_lds16(const void* g, void* l) {
  __builtin_amdgcn_global_load_lds(
      (const __attribute__((address_space(1))) unsigned int*)g,
      (__attribute__((address_space(3))) unsigned int*)l, 16, 0, 0);
}

// ---------------------------------------------------------------------------
// Sliding-window attention, permuted-fragment swapped structure (round 4) +
// this round: block-XOR V^T swizzle (conflict-free scatter writes), T14
// async staging (next tile's global loads issued before compute), exp2
// softmax (log2e folded into Q), mask skipped on fully-valid tiles.
// ---------------------------------------------------------------------------
__global__ __launch_bounds__(512, 2) void attn_kernel(const float* __restrict__ src,
                                                      float* __restrict__ attn_out) {
  const int bid = blockIdx.x;
  const int c = bid & 15;
  const int h = (bid >> 4) & 15;
  const int b = bid >> 8;
  const int tid = threadIdx.x;
  const int w = tid >> 6;
  const int lane = tid & 63;
  const int lg = lane >> 4;
  const int l16 = lane & 15;
  const size_t b4096 = (size_t)b * 4096;

  __shared__ __bf16 Ks[64][72];   // K tile row-major [key][d], pad 72 (144B = 9*16)
  __shared__ __bf16 Vt[64][72];   // V^T tile [d][key ^ 8*(d>>3)] block-XOR swizzled

  const int q0 = c * 256 + w * 32;
  const float LOG2E = 1.44269504f;

  // Q fragments (B-operand of swapped QK^T), pre-scaled by log2e
  bf16x8 qf[2][2];
#pragma unroll
  for (int qfi = 0; qfi < 2; ++qfi)
#pragma unroll
    for (int ks = 0; ks < 2; ++ks) {
      const int row = q0 + qfi * 16 + l16;
      const int d0 = ks * 32 + lg * 8;
      const float* p = src + (b4096 + row) * 1024 + h * 64 + d0;
      bf16x8 v;
#pragma unroll
      for (int j = 0; j < 8; ++j) v[j] = (__bf16)(p[j] * LOG2E);
      qf[qfi][ks] = v;
    }

  int krow[4];
#pragma unroll
  for (int kf = 0; kf < 4; ++kf)
    krow[kf] = ((kf >> 1) << 5) + ((l16 >> 2) << 3) + ((kf & 1) << 2) + (l16 & 3);

  const f32x4 z4 = {0.f, 0.f, 0.f, 0.f};
  float m_run[2], l_run[2];
  f32x4 o[2][4];
#pragma unroll
  for (int qfi = 0; qfi < 2; ++qfi) {
    m_run[qfi] = -6.0e8f;
    l_run[qfi] = 0.f;
#pragma unroll
    for (int df = 0; df < 4; ++df) o[qfi][df] = z4;
  }

  const int stage_key = tid >> 3;
  const int stage_d0 = (tid & 7) * 8;
  const int vcol = stage_key ^ stage_d0;  // 8*((d>>3)&7) == stage_d0 for this lane

  // prologue: issue loads for kt = 0
  int kpos = c * 256 - 256 + stage_key;
  float4 ga, gb;
  {
    const int rc = min(max(kpos, 0), 4095);
    const float* p = src + (b4096 + rc) * 1024 + h * 64 + stage_d0;
    ga = *(const float4*)p;
    gb = *(const float4*)(p + 4);
  }

  for (int kt = 0; kt < 12; ++kt) {
    const int kbase = c * 256 - 256 + kt * 64;
    // convert this tile's staged rows (auto-waits on the loads)
    bf16x8 kv;
    const bool inb = ((unsigned)kpos < 4096u);
    kv[0] = (__bf16)(inb ? ga.x : 0.f); kv[1] = (__bf16)(inb ? ga.y : 0.f);
    kv[2] = (__bf16)(inb ? ga.z : 0.f); kv[3] = (__bf16)(inb ? ga.w : 0.f);
    kv[4] = (__bf16)(inb ? gb.x : 0.f); kv[5] = (__bf16)(inb ? gb.y : 0.f);
    kv[6] = (__bf16)(inb ? gb.z : 0.f); kv[7] = (__bf16)(inb ? gb.w : 0.f);

    __syncthreads();  // all waves done computing tile kt-1
    *(bf16x8*)&Ks[stage_key][stage_d0] = kv;
#pragma unroll
    for (int j = 0; j < 8; ++j) Vt[stage_d0 + j][vcol] = kv[j];
    asm volatile("s_waitcnt lgkmcnt(0)" ::: "memory");
    __builtin_amdgcn_s_barrier();
    __builtin_amdgcn_sched_barrier(0);

    // T14: issue next tile's loads now; they retire under compute below
    kpos += 64;
    if (kt < 11) {
      const int rc = min(max(kpos, 0), 4095);
      const float* p = src + (b4096 + rc) * 1024 + h * 64 + stage_d0;
      ga = *(const float4*)p;
      gb = *(const float4*)(p + 4);
    }

    const bool skip = (kbase + 63 < 0) | (kbase >= 4096) |
                      (kbase + 63 < q0 - 256) | (kbase > q0 + 31 + 256);
    if (skip) continue;

    // ---- S^T = K_perm Q^T ----
    f32x4 s[4][2];
#pragma unroll
    for (int kf = 0; kf < 4; ++kf)
#pragma unroll
      for (int qfi = 0; qfi < 2; ++qfi) s[kf][qfi] = z4;

#pragma unroll
    for (int ks = 0; ks < 2; ++ks) {
      bf16x8 ka[4];
#pragma unroll
      for (int kf = 0; kf < 4; ++kf)
        ka[kf] = *(const bf16x8*)&Ks[krow[kf]][ks * 32 + lg * 8];
#pragma unroll
      for (int kf = 0; kf < 4; ++kf)
#pragma unroll
        for (int qfi = 0; qfi < 2; ++qfi)
          s[kf][qfi] = MFMA16(ka[kf], qf[qfi][ks], s[kf][qfi]);
    }

    // ---- mask only when the tile can violate the window/bounds ----
    const bool needmask = (kbase < 0) | (kbase > 4032) |
                          (kbase < q0 - 225) | (kbase > q0 + 193);
    if (needmask) {
#pragma unroll
      for (int qfi = 0; qfi < 2; ++qfi) {
        const int qp = q0 + qfi * 16 + l16;
#pragma unroll
        for (int kf = 0; kf < 4; ++kf) {
          const int kb0 = kbase + ((kf >> 1) << 5) + 8 * lg + ((kf & 1) << 2);
#pragma unroll
          for (int reg = 0; reg < 4; ++reg) {
            const int kp = kb0 + reg;
            const int rel = kp - qp;
            if (rel > 256 || rel < -256 || kp < 0 || kp >= 4096)
              s[kf][qfi][reg] = -1e9f;
          }
        }
      }
    }

    // ---- online softmax in log2 domain (q = l16, lane-local) ----
    bf16x4 pb[4][2];
#pragma unroll
    for (int qfi = 0; qfi < 2; ++qfi) {
      float tm = s[0][qfi][0];
#pragma unroll
      for (int kf = 0; kf < 4; ++kf)
#pragma unroll
        for (int reg = 0; reg < 4; ++reg) tm = fmaxf(tm, s[kf][qfi][reg]);
      tm = fmaxf(tm, __shfl_xor(tm, 16, 64));
      tm = fmaxf(tm, __shfl_xor(tm, 32, 64));

      const float mn = fmaxf(m_run[qfi], tm);
      const float scl = exp2f(m_run[qfi] - mn);
      m_run[qfi] = mn;

      float rs = 0.f;
#pragma unroll
      for (int kf = 0; kf < 4; ++kf) {
        bf16x4 pv;
#pragma unroll
        for (int reg = 0; reg < 4; ++reg) {
          const float p = exp2f(s[kf][qfi][reg] - mn);
          rs += p;
          pv[reg] = (__bf16)p;
        }
        pb[kf][qfi] = pv;
      }
      rs += __shfl_xor(rs, 16, 64);
      rs += __shfl_xor(rs, 32, 64);
      l_run[qfi] = l_run[qfi] * scl + rs;

#pragma unroll
      for (int df = 0; df < 4; ++df)
#pragma unroll
        for (int reg = 0; reg < 4; ++reg) o[qfi][df][reg] *= scl;
    }

    // ---- O^T += V^T P (A = swizzled Vt rows, B = pb concat in regs) ----
#pragma unroll
    for (int ks2 = 0; ks2 < 2; ++ks2) {
      bf16x8 av[4];
#pragma unroll
      for (int df = 0; df < 4; ++df) {
        const int d = df * 16 + l16;
        const int blk = (ks2 * 4 + lg) ^ (d >> 3);
        av[df] = *(const bf16x8*)&Vt[d][blk * 8];
      }
#pragma unroll
      for (int qfi = 0; qfi < 2; ++qfi) {
        const bf16x8 bq = __builtin_shufflevector(pb[2 * ks2][qfi], pb[2 * ks2 + 1][qfi],
                                                  0, 1, 2, 3, 4, 5, 6, 7);
#pragma unroll
        for (int df = 0; df < 4; ++df)
          o[qfi][df] = MFMA16(av[df], bq, o[qfi][df]);
      }
    }
  }

#pragma unroll
  for (int qfi = 0; qfi < 2; ++qfi) {
    const float inv = 1.0f / l_run[qfi];
    const int qp = q0 + qfi * 16 + l16;
    float* dst = attn_out + (b4096 + qp) * 1024 + h * 64 + lg * 4;
#pragma unroll
    for (int df = 0; df < 4; ++df) {
      float4 r;
      r.x = o[qfi][df][0] * inv;
      r.y = o[qfi][df][1] * inv;
      r.z = o[qfi][df][2] * inv;
      r.w = o[qfi][df][3] * inv;
      *(float4*)&dst[df * 16] = r;
    }
  }
}

// ---------------------------------------------------------------------------
// NT GEMM, BM=BN=256, BK=64, 8 waves (2M x 4N), per-wave 128x64.
// This round: 2 regions per K-tile {12 frag reads; stage 4 gloads;
// setprio MFMA x32; counted vmcnt(4); barrier; sched_barrier(0)} — no
// lgkmcnt(0) drains (compiler inserts precise per-register waits, m97).
// vmcnt ledger: at half-0 end in flight = khi(t)[4] + klo(t+1)[4] -> vmcnt(4)
// retires khi(t); at half-1 end = klo(t+1)[4] + khi(t+1)[4] -> retires klo(t+1).
// MODE 0: out bf16, +bias, relu.  MODE 1: out f32, split-K via blockIdx.y.
// ---------------------------------------------------------------------------
template <int MODE>
__global__ __launch_bounds__(512, 2) void gemm8p(const __bf16* __restrict__ A,
                                                 const __bf16* __restrict__ Bt,
                                                 const float* __restrict__ bias,
                                                 void* __restrict__ out0,
                                                 void* __restrict__ out1,
                                                 int M, int N, int Kstride, int Klen) {
  __shared__ char smem[131072];  // A: [0,64K) two 32K bufs; B: [64K,128K)
  const int tid = threadIdx.x;
  const int w = tid >> 6;
  const int lane = tid & 63;
  const int lg = lane >> 4;
  const int l16 = lane & 15;
  const int wr = w >> 2;  // 0..1 -> 128-row half
  const int wc = w & 3;   // 0..3 -> 64-col quarter

  const int nbn = N >> 8;
  const int x = ((int)blockIdx.x & 7) * ((int)gridDim.x >> 3) + ((int)blockIdx.x >> 3);
  const long bm = (long)(x / nbn) * 256;
  const long bn = (long)(x % nbn) * 256;
  const long koff = (long)blockIdx.y * Klen;
  void* out = blockIdx.y ? out1 : out0;

  const f32x4 z4 = {0.f, 0.f, 0.f, 0.f};
  f32x4 acc[8][4];
#pragma unroll
  for (int i = 0; i < 8; ++i)
#pragma unroll
    for (int j = 0; j < 4; ++j) acc[i][j] = z4;

  const int srow = tid >> 2;
  const int g0 = (tid & 3) ^ ((tid >> 3) & 3);
  const __bf16* Ag = A + (size_t)(bm + srow) * Kstride + koff + g0 * 8;
  const __bf16* Bg = Bt + (size_t)(bn + srow) * Kstride + koff + g0 * 8;

  auto stage = [&](int kt, int osel, int isB, int khalf) {
    const __bf16* src = (isB ? Bg : Ag) + (size_t)kt * 64 + khalf * 32;
    char* dst = smem + (isB ? 65536 : 0) + osel * 32768 + khalf * 16384 + (w << 10);
    gload_lds16(src, dst);
    gload_lds16(src + (size_t)128 * Kstride, dst + 8192);
  };

  const int lslot = (lg ^ ((l16 >> 1) & 3)) << 4;
  const char* pA = smem + (wr * 128 + l16) * 64 + lslot;
  const char* pB = smem + 65536 + (wc * 64 + l16) * 64 + lslot;
  auto rdA = [&](int sel, int rf, int ks) {
    return *(const bf16x8*)(pA + sel * 32768 + ks * 16384 + rf * 1024);
  };
  auto rdB = [&](int sel, int cf, int ks) {
    return *(const bf16x8*)(pB + sel * 32768 + ks * 16384 + cf * 1024);
  };

  const int NT = Klen >> 6;

  // prologue: stage tile 0 (8 loads); wait for the klo half
  stage(0, 0, 0, 0);
  stage(0, 0, 1, 0);
  stage(0, 0, 0, 1);
  stage(0, 0, 1, 1);
  asm volatile("s_waitcnt vmcnt(4)" ::: "memory");
  __builtin_amdgcn_s_barrier();
  __builtin_amdgcn_sched_barrier(0);

  for (int t = 0; t < NT; ++t) {
    const int sel = t & 1, osel = sel ^ 1;
    const bool st = (t + 1) < NT;
    bf16x8 af[8], bf[4];

    // ---------- half ks=0 ----------
#pragma unroll
    for (int rf = 0; rf < 8; ++rf) af[rf] = rdA(sel, rf, 0);
#pragma unroll
    for (int cf = 0; cf < 4; ++cf) bf[cf] = rdB(sel, cf, 0);
    if (st) { stage(t + 1, osel, 0, 0); stage(t + 1, osel, 1, 0); }
    __builtin_amdgcn_s_setprio(1);
#pragma unroll
    for (int rf = 0; rf < 8; ++rf)
#pragma unroll
      for (int cf = 0; cf < 4; ++cf)
        acc[rf][cf] = MFMA16(af[rf], bf[cf], acc[rf][cf]);
    __builtin_amdgcn_s_setprio(0);
    if (st) asm volatile("s_waitcnt vmcnt(4)" ::: "memory");
    else    asm volatile("s_waitcnt vmcnt(0)" ::: "memory");
    __builtin_amdgcn_s_barrier();
    __builtin_amdgcn_sched_barrier(0);

    // ---------- half ks=1 ----------
#pragma unroll
    for (int rf = 0; rf < 8; ++rf) af[rf] = rdA(sel, rf, 1);
#pragma unroll
    for (int cf = 0; cf < 4; ++cf) bf[cf] = rdB(sel, cf, 1);
    if (st) { stage(t + 1, osel, 0, 1); stage(t + 1, osel, 1, 1); }
    __builtin_amdgcn_s_setprio(1);
#pragma unroll
    for (int rf = 0; rf < 8; ++rf)
#pragma unroll
      for (int cf = 0; cf < 4; ++cf)
        acc[rf][cf] = MFMA16(af[rf], bf[cf], acc[rf][cf]);
    __builtin_amdgcn_s_setprio(0);
    if (st) asm volatile("s_waitcnt vmcnt(4)" ::: "memory");
    __builtin_amdgcn_s_barrier();
    __builtin_amdgcn_sched_barrier(0);
  }

  float bv[4];
  if (MODE == 0) {
#pragma unroll
    for (int cf = 0; cf < 4; ++cf) bv[cf] = bias[bn + wc * 64 + cf * 16 + l16];
  }
#pragma unroll
  for (int rf = 0; rf < 8; ++rf)
#pragma unroll
    for (int reg = 0; reg < 4; ++reg) {
      const long row = bm + wr * 128 + rf * 16 + lg * 4 + reg;
#pragma unroll
      for (int cf = 0; cf < 4; ++cf) {
        const long col = bn + wc * 64 + cf * 16 + l16;
        if (MODE == 0) {
          const float v = fmaxf(acc[rf][cf][reg] + bv[cf], 0.f);
          ((__bf16*)out)[row * N + col] = (__bf16)v;
        } else {
          ((float*)out)[row * N + col] = acc[rf][cf][reg];
        }
      }
    }
}

// ---------------------------------------------------------------------------
__global__ __launch_bounds__(256) void transpose_cvt(const float* __restrict__ in,
                                                     __bf16* __restrict__ out,
                                                     int R, int C) {
  __shared__ float tile[64][65];
  const long r0 = (long)blockIdx.y * 64;
  const long c0 = (long)blockIdx.x * 64;
  const int t = threadIdx.x;
  const int tr = t >> 6;
  const int tc = t & 63;
#pragma unroll
  for (int i = 0; i < 16; ++i) {
    const int r = tr * 16 + i;
    tile[r][tc] = in[(r0 + r) * C + c0 + tc];
  }
  __syncthreads();
#pragma unroll
  for (int i = 0; i < 16; ++i) {
    const int cc = tr * 16 + i;
    out[(c0 + cc) * (long)R + r0 + tc] = (__bf16)tile[tc][cc];
  }
}

// ---------------------------------------------------------------------------
__global__ __launch_bounds__(256) void ln1_kernel(const float* __restrict__ src,
                                                  const float* __restrict__ attn,
                                                  const float* __restrict__ g,
                                                  const float* __restrict__ bta,
                                                  __bf16* __restrict__ xb) {
  const long r = blockIdx.x;
  const int t = threadIdx.x;
  const float4 a = *(const float4*)&src[r * 1024 + t * 4];
  const float4 cc = *(const float4*)&attn[r * 1024 + t * 4];
  float v[4] = {a.x + cc.x, a.y + cc.y, a.z + cc.z, a.w + cc.w};
  float s = v[0] + v[1] + v[2] + v[3];
  float s2 = v[0] * v[0] + v[1] * v[1] + v[2] * v[2] + v[3] * v[3];
#pragma unroll
  for (int off = 32; off >= 1; off >>= 1) {
    s += __shfl_xor(s, off, 64);
    s2 += __shfl_xor(s2, off, 64);
  }
  __shared__ float red[8];
  if ((t & 63) == 0) { red[t >> 6] = s; red[(t >> 6) + 4] = s2; }
  __syncthreads();
  s = red[0] + red[1] + red[2] + red[3];
  s2 = red[4] + red[5] + red[6] + red[7];
  const float mu = s * (1.f / 1024.f);
  const float var = s2 * (1.f / 1024.f) - mu * mu;
  const float rstd = rsqrtf(var + 1e-5f);
  const float4 gv = *(const float4*)&g[t * 4];
  const float4 bv = *(const float4*)&bta[t * 4];
  bf16x4 y;
  y[0] = (__bf16)((v[0] - mu) * rstd * gv.x + bv.x);
  y[1] = (__bf16)((v[1] - mu) * rstd * gv.y + bv.y);
  y[2] = (__bf16)((v[2] - mu) * rstd * gv.z + bv.z);
  y[3] = (__bf16)((v[3] - mu) * rstd * gv.w + bv.w);
  *(bf16x4*)&xb[r * 1024 + t * 4] = y;
}

__global__ __launch_bounds__(256) void ln2_kernel(const __bf16* __restrict__ xb,
                                                  const float* __restrict__ f0,
                                                  const float* __restrict__ f1,
                                                  const float* __restrict__ b2,
                                                  const float* __restrict__ g,
                                                  const float* __restrict__ bta,
                                                  float* __restrict__ out) {
  const long r = blockIdx.x;
  const int t = threadIdx.x;
  const bf16x4 xv = *(const bf16x4*)&xb[r * 1024 + t * 4];
  const float4 f0v = *(const float4*)&f0[r * 1024 + t * 4];
  const float4 f1v = *(const float4*)&f1[r * 1024 + t * 4];
  const float4 b2v = *(const float4*)&b2[t * 4];
  float v[4] = {(float)xv[0] + f0v.x + f1v.x + b2v.x,
                (float)xv[1] + f0v.y + f1v.y + b2v.y,
                (float)xv[2] + f0v.z + f1v.z + b2v.z,
                (float)xv[3] + f0v.w + f1v.w + b2v.w};
  float s = v[0] + v[1] + v[2] + v[3];
  float s2 = v[0] * v[0] + v[1] * v[1] + v[2] * v[2] + v[3] * v[3];
#pragma unroll
  for (int off = 32; off >= 1; off >>= 1) {
    s += __shfl_xor(s, off, 64);
    s2 += __shfl_xor(s2, off, 64);
  }
  __shared__ float red[8];
  if ((t & 63) == 0) { red[t >> 6] = s; red[(t >> 6) + 4] = s2; }
  __syncthreads();
  s = red[0] + red[1] + red[2] + red[3];
  s2 = red[4] + red[5] + red[6] + red[7];
  const float mu = s * (1.f / 1024.f);
  const float var = s2 * (1.f / 1024.f) - mu * mu;
  const float rstd = rsqrtf(var + 1e-5f);
  const float4 gv = *(const float4*)&g[t * 4];
  const float4 bv = *(const float4*)&bta[t * 4];
  float4 y;
  y.x = (v[0] - mu) * rstd * gv.x + bv.x;
  y.y = (v[1] - mu) * rstd * gv.y + bv.y;
  y.z = (v[2] - mu) * rstd * gv.z + bv.z;
  y.w = (v[3] - mu) * rstd * gv.w + bv.w;
  *(float4*)&out[r * 1024 + t * 4] = y;
}

// ---------------------------------------------------------------------------
extern "C" void kernel_launch(void* const* d_in, const int* in_sizes, int n_in,
                              void* d_out, int out_size, void* d_ws, size_t ws_size,
                              hipStream_t stream) {
  const float* src = (const float*)d_in[0];
  const float* ln1_g = (const float*)d_in[1];
  const float* ln1_b = (const float*)d_in[2];
  const float* ln2_g = (const float*)d_in[3];
  const float* ln2_b = (const float*)d_in[4];
  const float* W1 = (const float*)d_in[5];
  const float* b1 = (const float*)d_in[6];
  const float* W2 = (const float*)d_in[7];
  const float* b2 = (const float*)d_in[8];
  float* out = (float*)d_out;
  char* ws = (char*)d_ws;

  const size_t MB = 1048576;
  float* ff0 = (float*)ws;                  // 32 MB (attn out, then FF half 0)
  float* ff1 = (float*)(ws + 32 * MB);      // 32 MB (FF half 1)
  __bf16* xb = (__bf16*)(ws + 64 * MB);     // 16 MB
  __bf16* w1t = (__bf16*)(ws + 80 * MB);    // 8 MB
  __bf16* w2t = (__bf16*)(ws + 88 * MB);    // 8 MB
  __bf16* hbuf = (__bf16*)(ws + 96 * MB);   // Mc*4096*2 B

  int Mc = 8192;
  while (Mc > 512 && 96 * MB + (size_t)Mc * 8192 > ws_size) Mc >>= 1;

  transpose_cvt<<<dim3(4096 / 64, 1024 / 64), 256, 0, stream>>>(W1, w1t, 1024, 4096);
  transpose_cvt<<<dim3(1024 / 64, 4096 / 64), 256, 0, stream>>>(W2, w2t, 4096, 1024);
  attn_kernel<<<512, 512, 0, stream>>>(src, ff0);
  ln1_kernel<<<8192, 256, 0, stream>>>(src, ff0, ln1_g, ln1_b, xb);
  for (int m0 = 0; m0 < 8192; m0 += Mc) {
    gemm8p<0><<<dim3((Mc / 256) * (4096 / 256), 1), 512, 0, stream>>>(
        xb + (size_t)m0 * 1024, w1t, b1, hbuf, hbuf, Mc, 4096, 1024, 1024);
    gemm8p<1><<<dim3((Mc / 256) * (1024 / 256), 2), 512, 0, stream>>>(
        hbuf, w2t, nullptr, ff0 + (size_t)m0 * 1024, ff1 + (size_t)m0 * 1024,
        Mc, 1024, 4096, 2048);
  }
  ln2_kernel<<<8192, 256, 0, stream>>>(xb, ff0, ff1, b2, ln2_g, ln2_b, out);
}

// Round 7
// 248.651 us; speedup vs baseline: 1.2846x; 1.0188x over previous
//
#include <hip/hip_runtime.h>

typedef __bf16 bf16x8 __attribute__((ext_vector_type(8)));
typedef __bf16 bf16x4 __attribute__((ext_vector_type(4)));
typedef float f32x4 __attribute__((ext_vector_type(4)));

#define MFMA16(a, b, c) __builtin_amdgcn_mfma_f32_16x16x32_bf16((a), (b), (c), 0, 0, 0)

__device__ __forceinline__ void gload_lds16(const void* g, void* l) {
  __builtin_amdgcn_global_load_lds(
      (const __attribute__((address_space(1))) unsigned int*)g,
      (__attribute__((address_space(3))) unsigned int*)l, 16, 0, 0);
}

// ---------------------------------------------------------------------------
// Sliding-window attention, permuted-fragment swapped structure + this round:
// double-buffered K/V (one barrier per tile) and defer-rescale (THR=8, log2).
// ---------------------------------------------------------------------------
__global__ __launch_bounds__(512, 2) void attn_kernel(const float* __restrict__ src,
                                                      float* __restrict__ attn_out) {
  const int bid = blockIdx.x;
  const int c = bid & 15;
  const int h = (bid >> 4) & 15;
  const int b = bid >> 8;
  const int tid = threadIdx.x;
  const int w = tid >> 6;
  const int lane = tid & 63;
  const int lg = lane >> 4;
  const int l16 = lane & 15;
  const size_t b4096 = (size_t)b * 4096;

  __shared__ __bf16 Ks[2][64][72];   // K tiles row-major [key][d], pad 72
  __shared__ __bf16 Vt[2][64][72];   // V^T tiles [d][key ^ 8*(d>>3)] swizzled

  const int q0 = c * 256 + w * 32;
  const float LOG2E = 1.44269504f;

  bf16x8 qf[2][2];
#pragma unroll
  for (int qfi = 0; qfi < 2; ++qfi)
#pragma unroll
    for (int ks = 0; ks < 2; ++ks) {
      const int row = q0 + qfi * 16 + l16;
      const int d0 = ks * 32 + lg * 8;
      const float* p = src + (b4096 + row) * 1024 + h * 64 + d0;
      bf16x8 v;
#pragma unroll
      for (int j = 0; j < 8; ++j) v[j] = (__bf16)(p[j] * LOG2E);
      qf[qfi][ks] = v;
    }

  int krow[4];
#pragma unroll
  for (int kf = 0; kf < 4; ++kf)
    krow[kf] = ((kf >> 1) << 5) + ((l16 >> 2) << 3) + ((kf & 1) << 2) + (l16 & 3);

  const f32x4 z4 = {0.f, 0.f, 0.f, 0.f};
  float m_run[2], l_run[2];
  f32x4 o[2][4];
#pragma unroll
  for (int qfi = 0; qfi < 2; ++qfi) {
    m_run[qfi] = -6.0e8f;
    l_run[qfi] = 0.f;
#pragma unroll
    for (int df = 0; df < 4; ++df) o[qfi][df] = z4;
  }

  const int stage_key = tid >> 3;
  const int stage_d0 = (tid & 7) * 8;
  const int vcol = stage_key ^ stage_d0;

  int kpos = c * 256 - 256 + stage_key;
  float4 ga, gb;
  {
    const int rc = min(max(kpos, 0), 4095);
    const float* p = src + (b4096 + rc) * 1024 + h * 64 + stage_d0;
    ga = *(const float4*)p;
    gb = *(const float4*)(p + 4);
  }

  for (int kt = 0; kt < 12; ++kt) {
    const int kbase = c * 256 - 256 + kt * 64;
    const int cur = kt & 1;
    // convert staged rows (auto-waits on the global loads)
    bf16x8 kv;
    const bool inb = ((unsigned)kpos < 4096u);
    kv[0] = (__bf16)(inb ? ga.x : 0.f); kv[1] = (__bf16)(inb ? ga.y : 0.f);
    kv[2] = (__bf16)(inb ? ga.z : 0.f); kv[3] = (__bf16)(inb ? ga.w : 0.f);
    kv[4] = (__bf16)(inb ? gb.x : 0.f); kv[5] = (__bf16)(inb ? gb.y : 0.f);
    kv[6] = (__bf16)(inb ? gb.z : 0.f); kv[7] = (__bf16)(inb ? gb.w : 0.f);

    // write into buf[cur]: its previous readers (tile kt-2) finished at the
    // barrier of tile kt-1, which this wave has already crossed.
    *(bf16x8*)&Ks[cur][stage_key][stage_d0] = kv;
#pragma unroll
    for (int j = 0; j < 8; ++j) Vt[cur][stage_d0 + j][vcol] = kv[j];
    asm volatile("s_waitcnt lgkmcnt(0)" ::: "memory");
    __builtin_amdgcn_s_barrier();   // publish buf[cur]; single barrier/tile
    __builtin_amdgcn_sched_barrier(0);

    // T14: next tile's loads retire under this tile's compute
    kpos += 64;
    if (kt < 11) {
      const int rc = min(max(kpos, 0), 4095);
      const float* p = src + (b4096 + rc) * 1024 + h * 64 + stage_d0;
      ga = *(const float4*)p;
      gb = *(const float4*)(p + 4);
    }

    const bool skip = (kbase + 63 < 0) | (kbase >= 4096) |
                      (kbase + 63 < q0 - 256) | (kbase > q0 + 31 + 256);
    if (skip) continue;

    // ---- S^T = K_perm Q^T ----
    f32x4 s[4][2];
#pragma unroll
    for (int kf = 0; kf < 4; ++kf)
#pragma unroll
      for (int qfi = 0; qfi < 2; ++qfi) s[kf][qfi] = z4;

#pragma unroll
    for (int ks = 0; ks < 2; ++ks) {
      bf16x8 ka[4];
#pragma unroll
      for (int kf = 0; kf < 4; ++kf)
        ka[kf] = *(const bf16x8*)&Ks[cur][krow[kf]][ks * 32 + lg * 8];
#pragma unroll
      for (int kf = 0; kf < 4; ++kf)
#pragma unroll
        for (int qfi = 0; qfi < 2; ++qfi)
          s[kf][qfi] = MFMA16(ka[kf], qf[qfi][ks], s[kf][qfi]);
    }

    const bool needmask = (kbase < 0) | (kbase > 4032) |
                          (kbase < q0 - 225) | (kbase > q0 + 193);
    if (needmask) {
#pragma unroll
      for (int qfi = 0; qfi < 2; ++qfi) {
        const int qp = q0 + qfi * 16 + l16;
#pragma unroll
        for (int kf = 0; kf < 4; ++kf) {
          const int kb0 = kbase + ((kf >> 1) << 5) + 8 * lg + ((kf & 1) << 2);
#pragma unroll
          for (int reg = 0; reg < 4; ++reg) {
            const int kp = kb0 + reg;
            const int rel = kp - qp;
            if (rel > 256 || rel < -256 || kp < 0 || kp >= 4096)
              s[kf][qfi][reg] = -1e9f;
          }
        }
      }
    }

    // ---- online softmax, log2 domain, defer-rescale THR=8 ----
    bf16x4 pb[4][2];
#pragma unroll
    for (int qfi = 0; qfi < 2; ++qfi) {
      float tm = s[0][qfi][0];
#pragma unroll
      for (int kf = 0; kf < 4; ++kf)
#pragma unroll
        for (int reg = 0; reg < 4; ++reg) tm = fmaxf(tm, s[kf][qfi][reg]);
      tm = fmaxf(tm, __shfl_xor(tm, 16, 64));
      tm = fmaxf(tm, __shfl_xor(tm, 32, 64));

      const bool nomax = __all(tm <= m_run[qfi] + 8.f);
      float scl = 1.f;
      if (!nomax) {
        const float mn = fmaxf(m_run[qfi], tm);
        scl = exp2f(m_run[qfi] - mn);
        m_run[qfi] = mn;
#pragma unroll
        for (int df = 0; df < 4; ++df)
#pragma unroll
          for (int reg = 0; reg < 4; ++reg) o[qfi][df][reg] *= scl;
      }
      const float mn = m_run[qfi];

      float rs = 0.f;
#pragma unroll
      for (int kf = 0; kf < 4; ++kf) {
        bf16x4 pv;
#pragma unroll
        for (int reg = 0; reg < 4; ++reg) {
          const float p = exp2f(s[kf][qfi][reg] - mn);
          rs += p;
          pv[reg] = (__bf16)p;
        }
        pb[kf][qfi] = pv;
      }
      rs += __shfl_xor(rs, 16, 64);
      rs += __shfl_xor(rs, 32, 64);
      l_run[qfi] = l_run[qfi] * scl + rs;
    }

    // ---- O^T += V^T P ----
#pragma unroll
    for (int ks2 = 0; ks2 < 2; ++ks2) {
      bf16x8 av[4];
#pragma unroll
      for (int df = 0; df < 4; ++df) {
        const int d = df * 16 + l16;
        const int blk = (ks2 * 4 + lg) ^ (d >> 3);
        av[df] = *(const bf16x8*)&Vt[cur][d][blk * 8];
      }
#pragma unroll
      for (int qfi = 0; qfi < 2; ++qfi) {
        const bf16x8 bq = __builtin_shufflevector(pb[2 * ks2][qfi], pb[2 * ks2 + 1][qfi],
                                                  0, 1, 2, 3, 4, 5, 6, 7);
#pragma unroll
        for (int df = 0; df < 4; ++df)
          o[qfi][df] = MFMA16(av[df], bq, o[qfi][df]);
      }
    }
  }

#pragma unroll
  for (int qfi = 0; qfi < 2; ++qfi) {
    const float inv = 1.0f / l_run[qfi];
    const int qp = q0 + qfi * 16 + l16;
    float* dst = attn_out + (b4096 + qp) * 1024 + h * 64 + lg * 4;
#pragma unroll
    for (int df = 0; df < 4; ++df) {
      float4 r;
      r.x = o[qfi][df][0] * inv;
      r.y = o[qfi][df][1] * inv;
      r.z = o[qfi][df][2] * inv;
      r.w = o[qfi][df][3] * inv;
      *(float4*)&dst[df * 16] = r;
    }
  }
}

// ---------------------------------------------------------------------------
// NT GEMM, BM=BN=256, 8 waves (2M x 4N), per-wave 128x64. This round: BK=32
// with a 4-slot LDS ring (4 x 32KB) -> tile t staged at iteration t-3, ~2.5
// tiles of compute in flight; per-iteration wait is vmcnt(8) (retire tile
// t+1, keep t+2/t+3 flying), then barrier publishes. One barrier per tile.
// Slot-XOR swizzle (2-way, free) on both staging source and ds_read.
// MODE 0: out bf16, +bias, relu.  MODE 1: out f32, split-K via blockIdx.y.
// ---------------------------------------------------------------------------
template <int MODE>
__global__ __launch_bounds__(512, 2) void gemm8p(const __bf16* __restrict__ A,
                                                 const __bf16* __restrict__ Bt,
                                                 const float* __restrict__ bias,
                                                 void* __restrict__ out0,
                                                 void* __restrict__ out1,
                                                 int M, int N, int Kstride, int Klen) {
  __shared__ char smem[131072];  // 4 bufs x 32KB; per buf: A 16K @0, B 16K @16384
  const int tid = threadIdx.x;
  const int w = tid >> 6;
  const int lane = tid & 63;
  const int lg = lane >> 4;
  const int l16 = lane & 15;
  const int wr = w >> 2;  // 0..1 -> 128-row half
  const int wc = w & 3;   // 0..3 -> 64-col quarter

  const int nbn = N >> 8;
  const int x = ((int)blockIdx.x & 7) * ((int)gridDim.x >> 3) + ((int)blockIdx.x >> 3);
  const long bm = (long)(x / nbn) * 256;
  const long bn = (long)(x % nbn) * 256;
  const long koff = (long)blockIdx.y * Klen;
  void* out = blockIdx.y ? out1 : out0;

  const f32x4 z4 = {0.f, 0.f, 0.f, 0.f};
  f32x4 acc[8][4];
#pragma unroll
  for (int i = 0; i < 8; ++i)
#pragma unroll
    for (int j = 0; j < 4; ++j) acc[i][j] = z4;

  // staging: per tile 4 gloads/thread (A u0,u1; B u0,u1), rows tid>>2 (+128)
  const int srow = tid >> 2;
  const int g0 = (tid & 3) ^ ((tid >> 3) & 3);  // inverse-swizzled source group
  const __bf16* Ag = A + (size_t)(bm + srow) * Kstride + koff + g0 * 8;
  const __bf16* Bg = Bt + (size_t)(bn + srow) * Kstride + koff + g0 * 8;

  auto stage = [&](int kt) {
    char* da = smem + ((kt & 3) << 15) + (w << 10);  // wave base; +lane*16 implicit
    const size_t o = (size_t)kt * 32;
    gload_lds16(Ag + o, da);
    gload_lds16(Ag + o + (size_t)128 * Kstride, da + 8192);
    gload_lds16(Bg + o, da + 16384);
    gload_lds16(Bg + o + (size_t)128 * Kstride, da + 16384 + 8192);
  };

  // fragment reads: row stride 64B, slot = lg ^ ((row>>1)&3)  (2-way, free)
  const int lslot = (lg ^ ((l16 >> 1) & 3)) << 4;
  const char* pA = smem + (wr * 128 + l16) * 64 + lslot;
  const char* pB = smem + 16384 + (wc * 64 + l16) * 64 + lslot;
  auto rdA = [&](int buf, int rf) {
    return *(const bf16x8*)(pA + (buf << 15) + rf * 1024);
  };
  auto rdB = [&](int buf, int cf) {
    return *(const bf16x8*)(pB + (buf << 15) + cf * 1024);
  };

  const int NT = Klen >> 5;

  // prologue: stage tiles 0..3; retire tile 0 (leave 1,2,3 = 12 in flight)
  stage(0); stage(1); stage(2); stage(3);
  asm volatile("s_waitcnt vmcnt(12)" ::: "memory");
  __builtin_amdgcn_s_barrier();
  __builtin_amdgcn_sched_barrier(0);

  for (int t = 0; t < NT; ++t) {
    const int buf = t & 3;
    // stage(t+3) overwrites tile t-1's slot: safe, all waves crossed barrier(t-1)
    if (t > 0 && t + 3 < NT) stage(t + 3);

    bf16x8 af[8], bf[4];
#pragma unroll
    for (int rf = 0; rf < 8; ++rf) af[rf] = rdA(buf, rf);
#pragma unroll
    for (int cf = 0; cf < 4; ++cf) bf[cf] = rdB(buf, cf);

    __builtin_amdgcn_s_setprio(1);
#pragma unroll
    for (int rf = 0; rf < 8; ++rf)
#pragma unroll
      for (int cf = 0; cf < 4; ++cf)
        acc[rf][cf] = MFMA16(af[rf], bf[cf], acc[rf][cf]);
    __builtin_amdgcn_s_setprio(0);

    // retire tile t+1's loads (own), then barrier publishes them block-wide
    const int nfly = min(2, NT - 2 - t);
    if (nfly >= 2)      asm volatile("s_waitcnt vmcnt(8)" ::: "memory");
    else if (nfly == 1) asm volatile("s_waitcnt vmcnt(4)" ::: "memory");
    else                asm volatile("s_waitcnt vmcnt(0)" ::: "memory");
    __builtin_amdgcn_s_barrier();
    __builtin_amdgcn_sched_barrier(0);
  }

  float bv[4];
  if (MODE == 0) {
#pragma unroll
    for (int cf = 0; cf < 4; ++cf) bv[cf] = bias[bn + wc * 64 + cf * 16 + l16];
  }
#pragma unroll
  for (int rf = 0; rf < 8; ++rf)
#pragma unroll
    for (int reg = 0; reg < 4; ++reg) {
      const long row = bm + wr * 128 + rf * 16 + lg * 4 + reg;
#pragma unroll
      for (int cf = 0; cf < 4; ++cf) {
        const long col = bn + wc * 64 + cf * 16 + l16;
        if (MODE == 0) {
          const float v = fmaxf(acc[rf][cf][reg] + bv[cf], 0.f);
          ((__bf16*)out)[row * N + col] = (__bf16)v;
        } else {
          ((float*)out)[row * N + col] = acc[rf][cf][reg];
        }
      }
    }
}

// ---------------------------------------------------------------------------
__global__ __launch_bounds__(256) void transpose_cvt(const float* __restrict__ in,
                                                     __bf16* __restrict__ out,
                                                     int R, int C) {
  __shared__ float tile[64][65];
  const long r0 = (long)blockIdx.y * 64;
  const long c0 = (long)blockIdx.x * 64;
  const int t = threadIdx.x;
  const int tr = t >> 6;
  const int tc = t & 63;
#pragma unroll
  for (int i = 0; i < 16; ++i) {
    const int r = tr * 16 + i;
    tile[r][tc] = in[(r0 + r) * C + c0 + tc];
  }
  __syncthreads();
#pragma unroll
  for (int i = 0; i < 16; ++i) {
    const int cc = tr * 16 + i;
    out[(c0 + cc) * (long)R + r0 + tc] = (__bf16)tile[tc][cc];
  }
}

// ---------------------------------------------------------------------------
__global__ __launch_bounds__(256) void ln1_kernel(const float* __restrict__ src,
                                                  const float* __restrict__ attn,
                                                  const float* __restrict__ g,
                                                  const float* __restrict__ bta,
                                                  __bf16* __restrict__ xb) {
  const long r = blockIdx.x;
  const int t = threadIdx.x;
  const float4 a = *(const float4*)&src[r * 1024 + t * 4];
  const float4 cc = *(const float4*)&attn[r * 1024 + t * 4];
  float v[4] = {a.x + cc.x, a.y + cc.y, a.z + cc.z, a.w + cc.w};
  float s = v[0] + v[1] + v[2] + v[3];
  float s2 = v[0] * v[0] + v[1] * v[1] + v[2] * v[2] + v[3] * v[3];
#pragma unroll
  for (int off = 32; off >= 1; off >>= 1) {
    s += __shfl_xor(s, off, 64);
    s2 += __shfl_xor(s2, off, 64);
  }
  __shared__ float red[8];
  if ((t & 63) == 0) { red[t >> 6] = s; red[(t >> 6) + 4] = s2; }
  __syncthreads();
  s = red[0] + red[1] + red[2] + red[3];
  s2 = red[4] + red[5] + red[6] + red[7];
  const float mu = s * (1.f / 1024.f);
  const float var = s2 * (1.f / 1024.f) - mu * mu;
  const float rstd = rsqrtf(var + 1e-5f);
  const float4 gv = *(const float4*)&g[t * 4];
  const float4 bv = *(const float4*)&bta[t * 4];
  bf16x4 y;
  y[0] = (__bf16)((v[0] - mu) * rstd * gv.x + bv.x);
  y[1] = (__bf16)((v[1] - mu) * rstd * gv.y + bv.y);
  y[2] = (__bf16)((v[2] - mu) * rstd * gv.z + bv.z);
  y[3] = (__bf16)((v[3] - mu) * rstd * gv.w + bv.w);
  *(bf16x4*)&xb[r * 1024 + t * 4] = y;
}

__global__ __launch_bounds__(256) void ln2_kernel(const __bf16* __restrict__ xb,
                                                  const float* __restrict__ f0,
                                                  const float* __restrict__ f1,
                                                  const float* __restrict__ b2,
                                                  const float* __restrict__ g,
                                                  const float* __restrict__ bta,
                                                  float* __restrict__ out) {
  const long r = blockIdx.x;
  const int t = threadIdx.x;
  const bf16x4 xv = *(const bf16x4*)&xb[r * 1024 + t * 4];
  const float4 f0v = *(const float4*)&f0[r * 1024 + t * 4];
  const float4 f1v = *(const float4*)&f1[r * 1024 + t * 4];
  const float4 b2v = *(const float4*)&b2[t * 4];
  float v[4] = {(float)xv[0] + f0v.x + f1v.x + b2v.x,
                (float)xv[1] + f0v.y + f1v.y + b2v.y,
                (float)xv[2] + f0v.z + f1v.z + b2v.z,
                (float)xv[3] + f0v.w + f1v.w + b2v.w};
  float s = v[0] + v[1] + v[2] + v[3];
  float s2 = v[0] * v[0] + v[1] * v[1] + v[2] * v[2] + v[3] * v[3];
#pragma unroll
  for (int off = 32; off >= 1; off >>= 1) {
    s += __shfl_xor(s, off, 64);
    s2 += __shfl_xor(s2, off, 64);
  }
  __shared__ float red[8];
  if ((t & 63) == 0) { red[t >> 6] = s; red[(t >> 6) + 4] = s2; }
  __syncthreads();
  s = red[0] + red[1] + red[2] + red[3];
  s2 = red[4] + red[5] + red[6] + red[7];
  const float mu = s * (1.f / 1024.f);
  const float var = s2 * (1.f / 1024.f) - mu * mu;
  const float rstd = rsqrtf(var + 1e-5f);
  const float4 gv = *(const float4*)&g[t * 4];
  const float4 bv = *(const float4*)&bta[t * 4];
  float4 y;
  y.x = (v[0] - mu) * rstd * gv.x + bv.x;
  y.y = (v[1] - mu) * rstd * gv.y + bv.y;
  y.z = (v[2] - mu) * rstd * gv.z + bv.z;
  y.w = (v[3] - mu) * rstd * gv.w + bv.w;
  *(float4*)&out[r * 1024 + t * 4] = y;
}

// ---------------------------------------------------------------------------
extern "C" void kernel_launch(void* const* d_in, const int* in_sizes, int n_in,
                              void* d_out, int out_size, void* d_ws, size_t ws_size,
                              hipStream_t stream) {
  const float* src = (const float*)d_in[0];
  const float* ln1_g = (const float*)d_in[1];
  const float* ln1_b = (const float*)d_in[2];
  const float* ln2_g = (const float*)d_in[3];
  const float* ln2_b = (const float*)d_in[4];
  const float* W1 = (const float*)d_in[5];
  const float* b1 = (const float*)d_in[6];
  const float* W2 = (const float*)d_in[7];
  const float* b2 = (const float*)d_in[8];
  float* out = (float*)d_out;
  char* ws = (char*)d_ws;

  const size_t MB = 1048576;
  float* ff0 = (float*)ws;                  // 32 MB (attn out, then FF half 0)
  float* ff1 = (float*)(ws + 32 * MB);      // 32 MB (FF half 1)
  __bf16* xb = (__bf16*)(ws + 64 * MB);     // 16 MB
  __bf16* w1t = (__bf16*)(ws + 80 * MB);    // 8 MB
  __bf16* w2t = (__bf16*)(ws + 88 * MB);    // 8 MB
  __bf16* hbuf = (__bf16*)(ws + 96 * MB);   // Mc*4096*2 B

  int Mc = 8192;
  while (Mc > 512 && 96 * MB + (size_t)Mc * 8192 > ws_size) Mc >>= 1;

  transpose_cvt<<<dim3(4096 / 64, 1024 / 64), 256, 0, stream>>>(W1, w1t, 1024, 4096);
  transpose_cvt<<<dim3(1024 / 64, 4096 / 64), 256, 0, stream>>>(W2, w2t, 4096, 1024);
  attn_kernel<<<512, 512, 0, stream>>>(src, ff0);
  ln1_kernel<<<8192, 256, 0, stream>>>(src, ff0, ln1_g, ln1_b, xb);
  for (int m0 = 0; m0 < 8192; m0 += Mc) {
    gemm8p<0><<<dim3((Mc / 256) * (4096 / 256), 1), 512, 0, stream>>>(
        xb + (size_t)m0 * 1024, w1t, b1, hbuf, hbuf, Mc, 4096, 1024, 1024);
    gemm8p<1><<<dim3((Mc / 256) * (1024 / 256), 2), 512, 0, stream>>>(
        hbuf, w2t, nullptr, ff0 + (size_t)m0 * 1024, ff1 + (size_t)m0 * 1024,
        Mc, 1024, 4096, 2048);
  }
  ln2_kernel<<<8192, 256, 0, stream>>>(xb, ff0, ff1, b2, ln2_g, ln2_b, out);
}

// Round 8
// 239.630 us; speedup vs baseline: 1.3329x; 1.0376x over previous
//
#include <hip/hip_runtime.h>

typedef __bf16 bf16x8 __attribute__((ext_vector_type(8)));
typedef __bf16 bf16x4 __attribute__((ext_vector_type(4)));
typedef float f32x4 __attribute__((ext_vector_type(4)));

#define MFMA16(a, b, c) __builtin_amdgcn_mfma_f32_16x16x32_bf16((a), (b), (c), 0, 0, 0)

__device__ __forceinline__ void gload_lds16(const void* g, void* l) {
  __builtin_amdgcn_global_load_lds(
      (const __attribute__((address_space(1))) unsigned int*)g,
      (__attribute__((address_space(3))) unsigned int*)l, 16, 0, 0);
}

// ---------------------------------------------------------------------------
// Sliding-window attention. This round: 4-wave blocks (q-span 128, 1024
// blocks) for cross-block TLP; bf16 output. Math identical to round 7
// (permuted-fragment swapped QK^T, dbuf K/V, defer-rescale THR=8, exp2).
// ---------------------------------------------------------------------------
__global__ __launch_bounds__(256, 2) void attn_kernel(const float* __restrict__ src,
                                                      __bf16* __restrict__ attn_out) {
  const int bid = blockIdx.x;
  const int half = bid & 1;
  const int c = (bid >> 1) & 15;
  const int h = (bid >> 5) & 15;
  const int b = bid >> 9;
  const int tid = threadIdx.x;
  const int w = tid >> 6;
  const int lane = tid & 63;
  const int lg = lane >> 4;
  const int l16 = lane & 15;
  const size_t b4096 = (size_t)b * 4096;

  __shared__ __bf16 Ks[2][64][72];   // K tiles row-major [key][d], pad 72
  __shared__ __bf16 Vt[2][64][72];   // V^T tiles [d][key ^ 8*(d>>3)] swizzled

  const int q0 = c * 256 + half * 128 + w * 32;
  const float LOG2E = 1.44269504f;

  bf16x8 qf[2][2];
#pragma unroll
  for (int qfi = 0; qfi < 2; ++qfi)
#pragma unroll
    for (int ks = 0; ks < 2; ++ks) {
      const int row = q0 + qfi * 16 + l16;
      const int d0 = ks * 32 + lg * 8;
      const float* p = src + (b4096 + row) * 1024 + h * 64 + d0;
      bf16x8 v;
#pragma unroll
      for (int j = 0; j < 8; ++j) v[j] = (__bf16)(p[j] * LOG2E);
      qf[qfi][ks] = v;
    }

  int krow[4];
#pragma unroll
  for (int kf = 0; kf < 4; ++kf)
    krow[kf] = ((kf >> 1) << 5) + ((l16 >> 2) << 3) + ((kf & 1) << 2) + (l16 & 3);

  const f32x4 z4 = {0.f, 0.f, 0.f, 0.f};
  float m_run[2], l_run[2];
  f32x4 o[2][4];
#pragma unroll
  for (int qfi = 0; qfi < 2; ++qfi) {
    m_run[qfi] = -6.0e8f;
    l_run[qfi] = 0.f;
#pragma unroll
    for (int df = 0; df < 4; ++df) o[qfi][df] = z4;
  }

  // staging: 256 threads, 64 rows x 64 dims f32 = 16 KB: 16 floats/thread
  const int stage_key = tid >> 2;
  const int d0a = (tid & 3) * 16;
  const int vcolA = stage_key ^ d0a;        // XOR with 8*(d>>3) for d in [d0a, d0a+8)
  const int vcolB = stage_key ^ (d0a + 8);  // for d in [d0a+8, d0a+16)

  int kpos = c * 256 - 256 + stage_key;
  float4 g4[4];
  {
    const int rc = min(max(kpos, 0), 4095);
    const float* p = src + (b4096 + rc) * 1024 + h * 64 + d0a;
#pragma unroll
    for (int i = 0; i < 4; ++i) g4[i] = *(const float4*)(p + i * 4);
  }

  for (int kt = 0; kt < 12; ++kt) {
    const int kbase = c * 256 - 256 + kt * 64;
    const int cur = kt & 1;
    bf16x8 kvA, kvB;
    const bool inb = ((unsigned)kpos < 4096u);
    kvA[0] = (__bf16)(inb ? g4[0].x : 0.f); kvA[1] = (__bf16)(inb ? g4[0].y : 0.f);
    kvA[2] = (__bf16)(inb ? g4[0].z : 0.f); kvA[3] = (__bf16)(inb ? g4[0].w : 0.f);
    kvA[4] = (__bf16)(inb ? g4[1].x : 0.f); kvA[5] = (__bf16)(inb ? g4[1].y : 0.f);
    kvA[6] = (__bf16)(inb ? g4[1].z : 0.f); kvA[7] = (__bf16)(inb ? g4[1].w : 0.f);
    kvB[0] = (__bf16)(inb ? g4[2].x : 0.f); kvB[1] = (__bf16)(inb ? g4[2].y : 0.f);
    kvB[2] = (__bf16)(inb ? g4[2].z : 0.f); kvB[3] = (__bf16)(inb ? g4[2].w : 0.f);
    kvB[4] = (__bf16)(inb ? g4[3].x : 0.f); kvB[5] = (__bf16)(inb ? g4[3].y : 0.f);
    kvB[6] = (__bf16)(inb ? g4[3].z : 0.f); kvB[7] = (__bf16)(inb ? g4[3].w : 0.f);

    *(bf16x8*)&Ks[cur][stage_key][d0a] = kvA;
    *(bf16x8*)&Ks[cur][stage_key][d0a + 8] = kvB;
#pragma unroll
    for (int j = 0; j < 8; ++j) Vt[cur][d0a + j][vcolA] = kvA[j];
#pragma unroll
    for (int j = 0; j < 8; ++j) Vt[cur][d0a + 8 + j][vcolB] = kvB[j];
    asm volatile("s_waitcnt lgkmcnt(0)" ::: "memory");
    __builtin_amdgcn_s_barrier();   // publish buf[cur]; one barrier per tile
    __builtin_amdgcn_sched_barrier(0);

    kpos += 64;
    if (kt < 11) {
      const int rc = min(max(kpos, 0), 4095);
      const float* p = src + (b4096 + rc) * 1024 + h * 64 + d0a;
#pragma unroll
      for (int i = 0; i < 4; ++i) g4[i] = *(const float4*)(p + i * 4);
    }

    const bool skip = (kbase + 63 < 0) | (kbase >= 4096) |
                      (kbase + 63 < q0 - 256) | (kbase > q0 + 31 + 256);
    if (skip) continue;

    // ---- S^T = K_perm Q^T ----
    f32x4 s[4][2];
#pragma unroll
    for (int kf = 0; kf < 4; ++kf)
#pragma unroll
      for (int qfi = 0; qfi < 2; ++qfi) s[kf][qfi] = z4;

#pragma unroll
    for (int ks = 0; ks < 2; ++ks) {
      bf16x8 ka[4];
#pragma unroll
      for (int kf = 0; kf < 4; ++kf)
        ka[kf] = *(const bf16x8*)&Ks[cur][krow[kf]][ks * 32 + lg * 8];
#pragma unroll
      for (int kf = 0; kf < 4; ++kf)
#pragma unroll
        for (int qfi = 0; qfi < 2; ++qfi)
          s[kf][qfi] = MFMA16(ka[kf], qf[qfi][ks], s[kf][qfi]);
    }

    const bool needmask = (kbase < 0) | (kbase > 4032) |
                          (kbase < q0 - 225) | (kbase > q0 + 193);
    if (needmask) {
#pragma unroll
      for (int qfi = 0; qfi < 2; ++qfi) {
        const int qp = q0 + qfi * 16 + l16;
#pragma unroll
        for (int kf = 0; kf < 4; ++kf) {
          const int kb0 = kbase + ((kf >> 1) << 5) + 8 * lg + ((kf & 1) << 2);
#pragma unroll
          for (int reg = 0; reg < 4; ++reg) {
            const int kp = kb0 + reg;
            const int rel = kp - qp;
            if (rel > 256 || rel < -256 || kp < 0 || kp >= 4096)
              s[kf][qfi][reg] = -1e9f;
          }
        }
      }
    }

    // ---- online softmax, log2 domain, defer-rescale THR=8 ----
    bf16x4 pb[4][2];
#pragma unroll
    for (int qfi = 0; qfi < 2; ++qfi) {
      float tm = s[0][qfi][0];
#pragma unroll
      for (int kf = 0; kf < 4; ++kf)
#pragma unroll
        for (int reg = 0; reg < 4; ++reg) tm = fmaxf(tm, s[kf][qfi][reg]);
      tm = fmaxf(tm, __shfl_xor(tm, 16, 64));
      tm = fmaxf(tm, __shfl_xor(tm, 32, 64));

      const bool nomax = __all(tm <= m_run[qfi] + 8.f);
      float scl = 1.f;
      if (!nomax) {
        const float mn = fmaxf(m_run[qfi], tm);
        scl = exp2f(m_run[qfi] - mn);
        m_run[qfi] = mn;
#pragma unroll
        for (int df = 0; df < 4; ++df)
#pragma unroll
          for (int reg = 0; reg < 4; ++reg) o[qfi][df][reg] *= scl;
      }
      const float mn = m_run[qfi];

      float rs = 0.f;
#pragma unroll
      for (int kf = 0; kf < 4; ++kf) {
        bf16x4 pv;
#pragma unroll
        for (int reg = 0; reg < 4; ++reg) {
          const float p = exp2f(s[kf][qfi][reg] - mn);
          rs += p;
          pv[reg] = (__bf16)p;
        }
        pb[kf][qfi] = pv;
      }
      rs += __shfl_xor(rs, 16, 64);
      rs += __shfl_xor(rs, 32, 64);
      l_run[qfi] = l_run[qfi] * scl + rs;
    }

    // ---- O^T += V^T P ----
#pragma unroll
    for (int ks2 = 0; ks2 < 2; ++ks2) {
      bf16x8 av[4];
#pragma unroll
      for (int df = 0; df < 4; ++df) {
        const int d = df * 16 + l16;
        const int blk = (ks2 * 4 + lg) ^ (d >> 3);
        av[df] = *(const bf16x8*)&Vt[cur][d][blk * 8];
      }
#pragma unroll
      for (int qfi = 0; qfi < 2; ++qfi) {
        const bf16x8 bq = __builtin_shufflevector(pb[2 * ks2][qfi], pb[2 * ks2 + 1][qfi],
                                                  0, 1, 2, 3, 4, 5, 6, 7);
#pragma unroll
        for (int df = 0; df < 4; ++df)
          o[qfi][df] = MFMA16(av[df], bq, o[qfi][df]);
      }
    }
  }

  // epilogue: O /= l ; bf16 out
#pragma unroll
  for (int qfi = 0; qfi < 2; ++qfi) {
    const float inv = 1.0f / l_run[qfi];
    const int qp = q0 + qfi * 16 + l16;
    __bf16* dst = attn_out + (b4096 + qp) * 1024 + h * 64 + lg * 4;
#pragma unroll
    for (int df = 0; df < 4; ++df) {
      bf16x4 y;
      y[0] = (__bf16)(o[qfi][df][0] * inv);
      y[1] = (__bf16)(o[qfi][df][1] * inv);
      y[2] = (__bf16)(o[qfi][df][2] * inv);
      y[3] = (__bf16)(o[qfi][df][3] * inv);
      *(bf16x4*)&dst[df * 16] = y;
    }
  }
}

// ---------------------------------------------------------------------------
// NT GEMM, BM=BN=256, BK=32, 4-slot LDS ring, counted vmcnt (round 7,
// best-so-far). MODE 0: out bf16 +bias +relu. MODE 1: out bf16 partial
// (no bias), split-K via blockIdx.y (stride ksplit_stride elements).
// ---------------------------------------------------------------------------
template <int MODE>
__global__ __launch_bounds__(512, 2) void gemm8p(const __bf16* __restrict__ A,
                                                 const __bf16* __restrict__ Bt,
                                                 const float* __restrict__ bias,
                                                 __bf16* __restrict__ out,
                                                 size_t ksplit_stride,
                                                 int M, int N, int Kstride, int Klen) {
  __shared__ char smem[131072];  // 4 bufs x 32KB; per buf: A 16K @0, B 16K @16384
  const int tid = threadIdx.x;
  const int w = tid >> 6;
  const int lane = tid & 63;
  const int lg = lane >> 4;
  const int l16 = lane & 15;
  const int wr = w >> 2;
  const int wc = w & 3;

  const int nbn = N >> 8;
  const int x = ((int)blockIdx.x & 7) * ((int)gridDim.x >> 3) + ((int)blockIdx.x >> 3);
  const long bm = (long)(x / nbn) * 256;
  const long bn = (long)(x % nbn) * 256;
  const long koff = (long)blockIdx.y * Klen;
  out += (size_t)blockIdx.y * ksplit_stride;

  const f32x4 z4 = {0.f, 0.f, 0.f, 0.f};
  f32x4 acc[8][4];
#pragma unroll
  for (int i = 0; i < 8; ++i)
#pragma unroll
    for (int j = 0; j < 4; ++j) acc[i][j] = z4;

  const int srow = tid >> 2;
  const int g0 = (tid & 3) ^ ((tid >> 3) & 3);
  const __bf16* Ag = A + (size_t)(bm + srow) * Kstride + koff + g0 * 8;
  const __bf16* Bg = Bt + (size_t)(bn + srow) * Kstride + koff + g0 * 8;

  auto stage = [&](int kt) {
    char* da = smem + ((kt & 3) << 15) + (w << 10);
    const size_t o = (size_t)kt * 32;
    gload_lds16(Ag + o, da);
    gload_lds16(Ag + o + (size_t)128 * Kstride, da + 8192);
    gload_lds16(Bg + o, da + 16384);
    gload_lds16(Bg + o + (size_t)128 * Kstride, da + 16384 + 8192);
  };

  const int lslot = (lg ^ ((l16 >> 1) & 3)) << 4;
  const char* pA = smem + (wr * 128 + l16) * 64 + lslot;
  const char* pB = smem + 16384 + (wc * 64 + l16) * 64 + lslot;
  auto rdA = [&](int buf, int rf) {
    return *(const bf16x8*)(pA + (buf << 15) + rf * 1024);
  };
  auto rdB = [&](int buf, int cf) {
    return *(const bf16x8*)(pB + (buf << 15) + cf * 1024);
  };

  const int NT = Klen >> 5;

  stage(0); stage(1); stage(2); stage(3);
  asm volatile("s_waitcnt vmcnt(12)" ::: "memory");
  __builtin_amdgcn_s_barrier();
  __builtin_amdgcn_sched_barrier(0);

  for (int t = 0; t < NT; ++t) {
    const int buf = t & 3;
    if (t > 0 && t + 3 < NT) stage(t + 3);

    bf16x8 af[8], bf[4];
#pragma unroll
    for (int rf = 0; rf < 8; ++rf) af[rf] = rdA(buf, rf);
#pragma unroll
    for (int cf = 0; cf < 4; ++cf) bf[cf] = rdB(buf, cf);

    __builtin_amdgcn_s_setprio(1);
#pragma unroll
    for (int rf = 0; rf < 8; ++rf)
#pragma unroll
      for (int cf = 0; cf < 4; ++cf)
        acc[rf][cf] = MFMA16(af[rf], bf[cf], acc[rf][cf]);
    __builtin_amdgcn_s_setprio(0);

    const int nfly = min(2, NT - 2 - t);
    if (nfly >= 2)      asm volatile("s_waitcnt vmcnt(8)" ::: "memory");
    else if (nfly == 1) asm volatile("s_waitcnt vmcnt(4)" ::: "memory");
    else                asm volatile("s_waitcnt vmcnt(0)" ::: "memory");
    __builtin_amdgcn_s_barrier();
    __builtin_amdgcn_sched_barrier(0);
  }

  float bv[4];
  if (MODE == 0) {
#pragma unroll
    for (int cf = 0; cf < 4; ++cf) bv[cf] = bias[bn + wc * 64 + cf * 16 + l16];
  }
#pragma unroll
  for (int rf = 0; rf < 8; ++rf)
#pragma unroll
    for (int reg = 0; reg < 4; ++reg) {
      const long row = bm + wr * 128 + rf * 16 + lg * 4 + reg;
#pragma unroll
      for (int cf = 0; cf < 4; ++cf) {
        const long col = bn + wc * 64 + cf * 16 + l16;
        if (MODE == 0) {
          out[row * N + col] = (__bf16)fmaxf(acc[rf][cf][reg] + bv[cf], 0.f);
        } else {
          out[row * N + col] = (__bf16)acc[rf][cf][reg];
        }
      }
    }
}

// ---------------------------------------------------------------------------
__global__ __launch_bounds__(256) void transpose_cvt(const float* __restrict__ in,
                                                     __bf16* __restrict__ out,
                                                     int R, int C) {
  __shared__ float tile[64][65];
  const long r0 = (long)blockIdx.y * 64;
  const long c0 = (long)blockIdx.x * 64;
  const int t = threadIdx.x;
  const int tr = t >> 6;
  const int tc = t & 63;
#pragma unroll
  for (int i = 0; i < 16; ++i) {
    const int r = tr * 16 + i;
    tile[r][tc] = in[(r0 + r) * C + c0 + tc];
  }
  __syncthreads();
#pragma unroll
  for (int i = 0; i < 16; ++i) {
    const int cc = tr * 16 + i;
    out[(c0 + cc) * (long)R + r0 + tc] = (__bf16)tile[tc][cc];
  }
}

// ---------------------------------------------------------------------------
__global__ __launch_bounds__(256) void ln1_kernel(const float* __restrict__ src,
                                                  const __bf16* __restrict__ attn,
                                                  const float* __restrict__ g,
                                                  const float* __restrict__ bta,
                                                  __bf16* __restrict__ xb) {
  const long r = blockIdx.x;
  const int t = threadIdx.x;
  const float4 a = *(const float4*)&src[r * 1024 + t * 4];
  const bf16x4 cc = *(const bf16x4*)&attn[r * 1024 + t * 4];
  float v[4] = {a.x + (float)cc[0], a.y + (float)cc[1],
                a.z + (float)cc[2], a.w + (float)cc[3]};
  float s = v[0] + v[1] + v[2] + v[3];
  float s2 = v[0] * v[0] + v[1] * v[1] + v[2] * v[2] + v[3] * v[3];
#pragma unroll
  for (int off = 32; off >= 1; off >>= 1) {
    s += __shfl_xor(s, off, 64);
    s2 += __shfl_xor(s2, off, 64);
  }
  __shared__ float red[8];
  if ((t & 63) == 0) { red[t >> 6] = s; red[(t >> 6) + 4] = s2; }
  __syncthreads();
  s = red[0] + red[1] + red[2] + red[3];
  s2 = red[4] + red[5] + red[6] + red[7];
  const float mu = s * (1.f / 1024.f);
  const float var = s2 * (1.f / 1024.f) - mu * mu;
  const float rstd = rsqrtf(var + 1e-5f);
  const float4 gv = *(const float4*)&g[t * 4];
  const float4 bv = *(const float4*)&bta[t * 4];
  bf16x4 y;
  y[0] = (__bf16)((v[0] - mu) * rstd * gv.x + bv.x);
  y[1] = (__bf16)((v[1] - mu) * rstd * gv.y + bv.y);
  y[2] = (__bf16)((v[2] - mu) * rstd * gv.z + bv.z);
  y[3] = (__bf16)((v[3] - mu) * rstd * gv.w + bv.w);
  *(bf16x4*)&xb[r * 1024 + t * 4] = y;
}

__global__ __launch_bounds__(256) void ln2_kernel(const __bf16* __restrict__ xb,
                                                  const __bf16* __restrict__ f0,
                                                  const __bf16* __restrict__ f1,
                                                  const float* __restrict__ b2,
                                                  const float* __restrict__ g,
                                                  const float* __restrict__ bta,
                                                  float* __restrict__ out) {
  const long r = blockIdx.x;
  const int t = threadIdx.x;
  const bf16x4 xv = *(const bf16x4*)&xb[r * 1024 + t * 4];
  const bf16x4 f0v = *(const bf16x4*)&f0[r * 1024 + t * 4];
  const bf16x4 f1v = *(const bf16x4*)&f1[r * 1024 + t * 4];
  const float4 b2v = *(const float4*)&b2[t * 4];
  float v[4];
#pragma unroll
  for (int i = 0; i < 4; ++i)
    v[i] = (float)xv[i] + (float)f0v[i] + (float)f1v[i] +
           ((const float*)&b2v)[i];
  float s = v[0] + v[1] + v[2] + v[3];
  float s2 = v[0] * v[0] + v[1] * v[1] + v[2] * v[2] + v[3] * v[3];
#pragma unroll
  for (int off = 32; off >= 1; off >>= 1) {
    s += __shfl_xor(s, off, 64);
    s2 += __shfl_xor(s2, off, 64);
  }
  __shared__ float red[8];
  if ((t & 63) == 0) { red[t >> 6] = s; red[(t >> 6) + 4] = s2; }
  __syncthreads();
  s = red[0] + red[1] + red[2] + red[3];
  s2 = red[4] + red[5] + red[6] + red[7];
  const float mu = s * (1.f / 1024.f);
  const float var = s2 * (1.f / 1024.f) - mu * mu;
  const float rstd = rsqrtf(var + 1e-5f);
  const float4 gv = *(const float4*)&g[t * 4];
  const float4 bv = *(const float4*)&bta[t * 4];
  float4 y;
  y.x = (v[0] - mu) * rstd * gv.x + bv.x;
  y.y = (v[1] - mu) * rstd * gv.y + bv.y;
  y.z = (v[2] - mu) * rstd * gv.z + bv.z;
  y.w = (v[3] - mu) * rstd * gv.w + bv.w;
  *(float4*)&out[r * 1024 + t * 4] = y;
}

// ---------------------------------------------------------------------------
extern "C" void kernel_launch(void* const* d_in, const int* in_sizes, int n_in,
                              void* d_out, int out_size, void* d_ws, size_t ws_size,
                              hipStream_t stream) {
  const float* src = (const float*)d_in[0];
  const float* ln1_g = (const float*)d_in[1];
  const float* ln1_b = (const float*)d_in[2];
  const float* ln2_g = (const float*)d_in[3];
  const float* ln2_b = (const float*)d_in[4];
  const float* W1 = (const float*)d_in[5];
  const float* b1 = (const float*)d_in[6];
  const float* W2 = (const float*)d_in[7];
  const float* b2 = (const float*)d_in[8];
  float* out = (float*)d_out;
  char* ws = (char*)d_ws;

  const size_t MB = 1048576;
  __bf16* xb = (__bf16*)ws;                  // @0   16 MB
  __bf16* attn_b = (__bf16*)(ws + 16 * MB);  // @16  16 MB (also ff0b later)
  __bf16* ffb = attn_b;                      // ff partials: @16 + k*16MB
  __bf16* ff1b = (__bf16*)(ws + 32 * MB);    // @32  16 MB
  __bf16* w1t = (__bf16*)(ws + 48 * MB);     // @48  8 MB
  __bf16* w2t = (__bf16*)(ws + 56 * MB);     // @56  8 MB
  __bf16* hbuf = (__bf16*)(ws + 64 * MB);    // @64  Mc*4096*2 B (64 MB at Mc=8192)

  int Mc = 8192;
  while (Mc > 512 && 64 * MB + (size_t)Mc * 8192 > ws_size) Mc >>= 1;

  transpose_cvt<<<dim3(4096 / 64, 1024 / 64), 256, 0, stream>>>(W1, w1t, 1024, 4096);
  transpose_cvt<<<dim3(1024 / 64, 4096 / 64), 256, 0, stream>>>(W2, w2t, 4096, 1024);
  attn_kernel<<<1024, 256, 0, stream>>>(src, attn_b);
  ln1_kernel<<<8192, 256, 0, stream>>>(src, attn_b, ln1_g, ln1_b, xb);
  for (int m0 = 0; m0 < 8192; m0 += Mc) {
    gemm8p<0><<<dim3((Mc / 256) * (4096 / 256), 1), 512, 0, stream>>>(
        xb + (size_t)m0 * 1024, w1t, b1, hbuf, 0, Mc, 4096, 1024, 1024);
    gemm8p<1><<<dim3((Mc / 256) * (1024 / 256), 2), 512, 0, stream>>>(
        hbuf, w2t, nullptr, ffb + (size_t)m0 * 1024, (size_t)8192 * 1024,
        Mc, 1024, 4096, 2048);
  }
  ln2_kernel<<<8192, 256, 0, stream>>>(xb, ffb, ff1b, b2, ln2_g, ln2_b, out);
}